// Round 1
// baseline (616.161 us; speedup 1.0000x reference)
//
#include <hip/hip_runtime.h>
#include <hip/hip_bf16.h>
#include <cstdint>

#define NH   32
#define NKV  8
#define HD   64
#define CE   2048      // n_embd
#define BB   2
#define TT   2048
#define QKVD 3072      // (32 + 2*8) * 64
#define MM   (BB*TT)   // 4096 rows

typedef float  f32x4 __attribute__((ext_vector_type(4)));
typedef short  s16x8 __attribute__((ext_vector_type(8)));
typedef unsigned short u16;

static __device__ __forceinline__ float bf2f(u16 u) {
    union { uint32_t u; float f; } v; v.u = ((uint32_t)u) << 16; return v.f;
}
static __device__ __forceinline__ u16 f2bf(float f) {
    union { float f; uint32_t u; } v; v.f = f;
    uint32_t r = v.u + 0x7fffu + ((v.u >> 16) & 1u);   // RNE
    return (u16)(r >> 16);
}

// ---------------- fp32 -> bf16 convert (vectorized 8/thread) ----------------
__global__ void k_f32_to_bf16(const float* __restrict__ in, u16* __restrict__ out, int n8) {
    int i = blockIdx.x * blockDim.x + threadIdx.x;
    if (i >= n8) return;
    const float4* p = reinterpret_cast<const float4*>(in) + (size_t)i * 2;
    float4 a = p[0], b = p[1];
    s16x8 v;
    v[0] = (short)f2bf(a.x); v[1] = (short)f2bf(a.y);
    v[2] = (short)f2bf(a.z); v[3] = (short)f2bf(a.w);
    v[4] = (short)f2bf(b.x); v[5] = (short)f2bf(b.y);
    v[6] = (short)f2bf(b.z); v[7] = (short)f2bf(b.w);
    *reinterpret_cast<s16x8*>(out + (size_t)i * 8) = v;
}

// ---------------- bf16 GEMM: C(M,N) = A(M,K) @ B(N,K)^T ----------------
// 128x128 tile, BK=32, 4 waves (2x2), each wave 64x64 via 4x4 16x16x32 MFMAs.
template<bool OUT_BF16>
__global__ __launch_bounds__(256) void k_gemm_bt(const u16* __restrict__ A,
                                                 const u16* __restrict__ Bm,
                                                 void* __restrict__ Cout,
                                                 int M, int N, int K) {
    __shared__ u16 As[128][40];   // +8 pad: 80B row stride -> 2-way (free) on b128 reads
    __shared__ u16 Bs[128][40];
    const int tid  = threadIdx.x;
    const int m0   = blockIdx.y * 128;
    const int n0   = blockIdx.x * 128;
    const int w    = tid >> 6;
    const int lane = tid & 63;
    const int lr   = lane & 15, lg = lane >> 4;
    const int wm   = (w >> 1) * 64, wn = (w & 1) * 64;

    f32x4 acc[4][4] = {};

    for (int k0 = 0; k0 < K; k0 += 32) {
        #pragma unroll
        for (int rep = 0; rep < 2; ++rep) {
            int ch = tid + rep * 256;       // 512 chunks of 16B per tile
            int r = ch >> 2, c = ch & 3;
            *reinterpret_cast<s16x8*>(&As[r][c * 8]) =
                *reinterpret_cast<const s16x8*>(A + (size_t)(m0 + r) * K + k0 + c * 8);
            *reinterpret_cast<s16x8*>(&Bs[r][c * 8]) =
                *reinterpret_cast<const s16x8*>(Bm + (size_t)(n0 + r) * K + k0 + c * 8);
        }
        __syncthreads();
        s16x8 af[4], bf[4];
        #pragma unroll
        for (int i = 0; i < 4; ++i)
            af[i] = *reinterpret_cast<const s16x8*>(&As[wm + i * 16 + lr][lg * 8]);
        #pragma unroll
        for (int j = 0; j < 4; ++j)
            bf[j] = *reinterpret_cast<const s16x8*>(&Bs[wn + j * 16 + lr][lg * 8]);
        #pragma unroll
        for (int i = 0; i < 4; ++i)
            #pragma unroll
            for (int j = 0; j < 4; ++j)
                acc[i][j] = __builtin_amdgcn_mfma_f32_16x16x32_bf16(af[i], bf[j], acc[i][j], 0, 0, 0);
        __syncthreads();
    }

    #pragma unroll
    for (int i = 0; i < 4; ++i) {
        #pragma unroll
        for (int j = 0; j < 4; ++j) {
            #pragma unroll
            for (int r = 0; r < 4; ++r) {
                int m = m0 + wm + i * 16 + lg * 4 + r;
                int n = n0 + wn + j * 16 + lr;
                if constexpr (OUT_BF16)
                    reinterpret_cast<u16*>(Cout)[(size_t)m * N + n] = f2bf(acc[i][j][r]);
                else
                    reinterpret_cast<float*>(Cout)[(size_t)m * N + n] = acc[i][j][r];
            }
        }
    }
}

// ---------------- RoPE + scatter into Q (B,H,T,D), K (B,KVH,T,D), Vt (B,KVH,D,T) ----------------
__global__ void k_rope_scatter(const u16* __restrict__ qkv,
                               const float* __restrict__ fcos,
                               const float* __restrict__ fsin,
                               u16* __restrict__ Q,
                               u16* __restrict__ Kb,
                               u16* __restrict__ Vt) {
    int p = blockIdx.x * blockDim.x + threadIdx.x;       // pair index
    if (p >= MM * (QKVD / 2)) return;
    int row = p / (QKVD / 2);
    int f   = (p % (QKVD / 2)) * 2;
    int b = row / TT, t = row % TT;
    uint32_t pk = reinterpret_cast<const uint32_t*>(qkv)[(size_t)row * (QKVD / 2) + (f >> 1)];
    u16 u0 = (u16)(pk & 0xffff), u1 = (u16)(pk >> 16);
    if (f < NH * HD) {                       // Q with RoPE
        int h = f / HD, d = f % HD;
        float c = fcos[t * 32 + (d >> 1)], s = fsin[t * 32 + (d >> 1)];
        float x0 = bf2f(u0), x1 = bf2f(u1);
        uint32_t o = (uint32_t)f2bf(x0 * c - x1 * s) | ((uint32_t)f2bf(x0 * s + x1 * c) << 16);
        *reinterpret_cast<uint32_t*>(Q + ((size_t)((b * NH + h) * TT + t)) * HD + d) = o;
    } else if (f < NH * HD + NKV * HD) {     // K with RoPE
        int fk = f - NH * HD;
        int h = fk / HD, d = fk % HD;
        float c = fcos[t * 32 + (d >> 1)], s = fsin[t * 32 + (d >> 1)];
        float x0 = bf2f(u0), x1 = bf2f(u1);
        uint32_t o = (uint32_t)f2bf(x0 * c - x1 * s) | ((uint32_t)f2bf(x0 * s + x1 * c) << 16);
        *reinterpret_cast<uint32_t*>(Kb + ((size_t)((b * NKV + h) * TT + t)) * HD + d) = o;
    } else {                                 // V, transposed store (d-major)
        int fv = f - NH * HD - NKV * HD;
        int h = fv / HD, d = fv % HD;
        Vt[((size_t)(b * NKV + h) * HD + d) * TT + t]     = u0;
        Vt[((size_t)(b * NKV + h) * HD + d + 1) * TT + t] = u1;
    }
}

// ---------------- causal GQA flash attention ----------------
// grid (T/64, NH, B), 256 threads = 4 waves; wave w owns 16 q-rows.
// K/V fragments read directly from global (KV per (b,kvh) = 512 KB, L2-fits).
__global__ __launch_bounds__(256) void k_attn(const u16* __restrict__ Q,
                                              const u16* __restrict__ Kb,
                                              const u16* __restrict__ Vt,
                                              u16* __restrict__ Y) {
    __shared__ u16 Plds[4][16][40];          // per-wave P tile, padded
    const int tid = threadIdx.x;
    const int w = tid >> 6, lane = tid & 63;
    const int lr = lane & 15, lg = lane >> 4;
    const int b = blockIdx.z, h = blockIdx.y, kvh = h >> 2;
    const int q0 = blockIdx.x * 64 + w * 16;

    const u16* qbase = Q  + ((size_t)(b * NH  + h  ) * TT) * HD;
    const u16* kbase = Kb + ((size_t)(b * NKV + kvh) * TT) * HD;
    const u16* vbase = Vt + ((size_t)(b * NKV + kvh) * HD) * TT;

    s16x8 aq0 = *reinterpret_cast<const s16x8*>(qbase + (size_t)(q0 + lr) * HD + lg * 8);
    s16x8 aq1 = *reinterpret_cast<const s16x8*>(qbase + (size_t)(q0 + lr) * HD + 32 + lg * 8);

    float mrow[4] = {-1e30f, -1e30f, -1e30f, -1e30f};
    float lrow[4] = {0.f, 0.f, 0.f, 0.f};
    f32x4 oacc[4] = {};
    const float scale = 0.125f;              // 1/sqrt(64)

    const int kvend = q0 + 15;               // inclusive causal limit of this wave
    for (int kv0 = 0; kv0 <= kvend; kv0 += 32) {
        s16x8 bk0a = *reinterpret_cast<const s16x8*>(kbase + (size_t)(kv0 + lr) * HD + lg * 8);
        s16x8 bk0b = *reinterpret_cast<const s16x8*>(kbase + (size_t)(kv0 + lr) * HD + 32 + lg * 8);
        s16x8 bk1a = *reinterpret_cast<const s16x8*>(kbase + (size_t)(kv0 + 16 + lr) * HD + lg * 8);
        s16x8 bk1b = *reinterpret_cast<const s16x8*>(kbase + (size_t)(kv0 + 16 + lr) * HD + 32 + lg * 8);
        f32x4 s0 = {}, s1 = {};
        s0 = __builtin_amdgcn_mfma_f32_16x16x32_bf16(aq0, bk0a, s0, 0, 0, 0);
        s0 = __builtin_amdgcn_mfma_f32_16x16x32_bf16(aq1, bk0b, s0, 0, 0, 0);
        s1 = __builtin_amdgcn_mfma_f32_16x16x32_bf16(aq0, bk1a, s1, 0, 0, 0);
        s1 = __builtin_amdgcn_mfma_f32_16x16x32_bf16(aq1, bk1b, s1, 0, 0, 0);

        float sv[2][4];
        #pragma unroll
        for (int r = 0; r < 4; ++r) {
            int qrow = q0 + lg * 4 + r;
            sv[0][r] = (kv0 + lr      <= qrow) ? s0[r] * scale : -1e30f;
            sv[1][r] = (kv0 + 16 + lr <= qrow) ? s1[r] * scale : -1e30f;
        }
        float tmax[4], tsum[4], alpha[4], pv0[4], pv1[4];
        #pragma unroll
        for (int r = 0; r < 4; ++r) tmax[r] = fmaxf(sv[0][r], sv[1][r]);
        #pragma unroll
        for (int d = 1; d < 16; d <<= 1)
            #pragma unroll
            for (int r = 0; r < 4; ++r)
                tmax[r] = fmaxf(tmax[r], __shfl_xor(tmax[r], d, 64));
        #pragma unroll
        for (int r = 0; r < 4; ++r) {
            float mn = fmaxf(mrow[r], tmax[r]);
            alpha[r] = __expf(mrow[r] - mn);
            mrow[r] = mn;
            pv0[r] = __expf(sv[0][r] - mn);
            pv1[r] = __expf(sv[1][r] - mn);
            tsum[r] = pv0[r] + pv1[r];
        }
        #pragma unroll
        for (int d = 1; d < 16; d <<= 1)
            #pragma unroll
            for (int r = 0; r < 4; ++r)
                tsum[r] += __shfl_xor(tsum[r], d, 64);
        #pragma unroll
        for (int r = 0; r < 4; ++r) lrow[r] = lrow[r] * alpha[r] + tsum[r];
        #pragma unroll
        for (int db = 0; db < 4; ++db)
            #pragma unroll
            for (int r = 0; r < 4; ++r)
                oacc[db][r] *= alpha[r];

        // P (D-layout) -> LDS -> reload in A-fragment layout
        #pragma unroll
        for (int r = 0; r < 4; ++r) {
            Plds[w][lg * 4 + r][lr]      = f2bf(pv0[r]);
            Plds[w][lg * 4 + r][16 + lr] = f2bf(pv1[r]);
        }
        asm volatile("s_waitcnt lgkmcnt(0)" ::: "memory");   // wave-local LDS fence
        __builtin_amdgcn_sched_barrier(0);
        s16x8 pa = *reinterpret_cast<const s16x8*>(&Plds[w][lr][lg * 8]);

        #pragma unroll
        for (int db = 0; db < 4; ++db) {
            s16x8 bv = *reinterpret_cast<const s16x8*>(vbase + (size_t)(db * 16 + lr) * TT + kv0 + lg * 8);
            oacc[db] = __builtin_amdgcn_mfma_f32_16x16x32_bf16(pa, bv, oacc[db], 0, 0, 0);
        }
    }

    #pragma unroll
    for (int db = 0; db < 4; ++db)
        #pragma unroll
        for (int r = 0; r < 4; ++r) {
            int t = q0 + lg * 4 + r;
            Y[((size_t)(b * TT + t) * NH + h) * HD + db * 16 + lr] = f2bf(oacc[db][r] / lrow[r]);
        }
}

// ---------------- launch ----------------
extern "C" void kernel_launch(void* const* d_in, const int* in_sizes, int n_in,
                              void* d_out, int out_size, void* d_ws, size_t ws_size,
                              hipStream_t stream) {
    (void)in_sizes; (void)n_in; (void)out_size; (void)ws_size;
    const float* x     = (const float*)d_in[0];
    const float* wqkv  = (const float*)d_in[1];
    const float* wproj = (const float*)d_in[2];
    const float* fcos  = (const float*)d_in[3];
    const float* fsin  = (const float*)d_in[4];

    char* ws = (char*)d_ws;
    size_t off = 0;
    auto alloc = [&](size_t bytes) { void* p = ws + off; off += (bytes + 255) & ~(size_t)255; return p; };
    u16* Xbf  = (u16*)alloc((size_t)MM * CE * 2);
    u16* Wqb  = (u16*)alloc((size_t)QKVD * CE * 2);
    u16* Wpb  = (u16*)alloc((size_t)CE * CE * 2);
    u16* QKVb = (u16*)alloc((size_t)MM * QKVD * 2);
    u16* Qb   = (u16*)alloc((size_t)BB * NH * TT * HD * 2);
    u16* Kbuf = (u16*)alloc((size_t)BB * NKV * TT * HD * 2);
    u16* Vtb  = (u16*)alloc((size_t)BB * NKV * HD * TT * 2);
    u16* Yb   = (u16*)alloc((size_t)MM * CE * 2);

    k_f32_to_bf16<<<(MM * CE / 8 + 255) / 256, 256, 0, stream>>>(x, Xbf, MM * CE / 8);
    k_f32_to_bf16<<<(QKVD * CE / 8 + 255) / 256, 256, 0, stream>>>(wqkv, Wqb, QKVD * CE / 8);
    k_f32_to_bf16<<<(CE * CE / 8 + 255) / 256, 256, 0, stream>>>(wproj, Wpb, CE * CE / 8);

    dim3 g1(QKVD / 128, MM / 128);
    k_gemm_bt<true><<<g1, 256, 0, stream>>>(Xbf, Wqb, QKVb, MM, QKVD, CE);

    int pairs = MM * (QKVD / 2);
    k_rope_scatter<<<(pairs + 255) / 256, 256, 0, stream>>>(QKVb, fcos, fsin, Qb, Kbuf, Vtb);

    dim3 ga(TT / 64, NH, BB);
    k_attn<<<ga, 256, 0, stream>>>(Qb, Kbuf, Vtb, Yb);

    dim3 g2(CE / 128, MM / 128);
    k_gemm_bt<false><<<g2, 256, 0, stream>>>(Yb, Wpb, d_out, MM, CE, CE);
}

// Round 2
// 295.890 us; speedup vs baseline: 2.0824x; 2.0824x over previous
//
#include <hip/hip_runtime.h>
#include <hip/hip_bf16.h>
#include <cstdint>

#define NH   32
#define NKV  8
#define HD   64
#define CE   2048      // n_embd
#define BB   2
#define TT   2048
#define QKVD 3072      // (32 + 2*8) * 64
#define MM   (BB*TT)   // 4096 rows
#define NTILE (TT/64)  // 32 q-tiles of 64

typedef float  f32x4 __attribute__((ext_vector_type(4)));
typedef short  s16x8 __attribute__((ext_vector_type(8)));
typedef unsigned short u16;

#define AS1 __attribute__((address_space(1)))
#define AS3 __attribute__((address_space(3)))
#define GLDS16(src, dst) __builtin_amdgcn_global_load_lds( \
    (const AS1 uint32_t*)(src), (AS3 uint32_t*)(dst), 16, 0, 0)

static __device__ __forceinline__ float bf2f(u16 u) {
    union { uint32_t u; float f; } v; v.u = ((uint32_t)u) << 16; return v.f;
}
static __device__ __forceinline__ u16 f2bf(float f) {
    union { float f; uint32_t u; } v; v.f = f;
    uint32_t r = v.u + 0x7fffu + ((v.u >> 16) & 1u);   // RNE
    return (u16)(r >> 16);
}

// ---------------- fp32 -> bf16 convert (vectorized 8/thread) ----------------
__global__ void k_f32_to_bf16(const float* __restrict__ in, u16* __restrict__ out, int n8) {
    int i = blockIdx.x * blockDim.x + threadIdx.x;
    if (i >= n8) return;
    const float4* p = reinterpret_cast<const float4*>(in) + (size_t)i * 2;
    float4 a = p[0], b = p[1];
    s16x8 v;
    v[0] = (short)f2bf(a.x); v[1] = (short)f2bf(a.y);
    v[2] = (short)f2bf(a.z); v[3] = (short)f2bf(a.w);
    v[4] = (short)f2bf(b.x); v[5] = (short)f2bf(b.y);
    v[6] = (short)f2bf(b.z); v[7] = (short)f2bf(b.w);
    *reinterpret_cast<s16x8*>(out + (size_t)i * 8) = v;
}

// ---------------- bf16 GEMM (m97 structure): C(M,N) = A(M,K) @ B(N,K)^T ----------------
// 128x128 tile, BK=32, linear LDS, global_load_lds width-16 staging.
template<bool OUT_BF16>
__global__ __launch_bounds__(256) void k_gemm_bt(const u16* __restrict__ A,
                                                 const u16* __restrict__ Bm,
                                                 void* __restrict__ Cout,
                                                 int M, int N, int K) {
    __shared__ u16 As[128 * 32];
    __shared__ u16 Bs[128 * 32];
    const int tid  = threadIdx.x;
    const int m0   = blockIdx.y * 128;
    const int n0   = blockIdx.x * 128;
    const int w    = tid >> 6;
    const int lane = tid & 63;
    const int lr   = lane & 15, lg = lane >> 4;
    const int wm   = (w >> 1) * 64, wn = (w & 1) * 64;

    // staging thread-constants: chunk o = w*2048 + c*1024 + lane*16 bytes (row=64B)
    const int o0 = w * 2048 + lane * 16, o1 = o0 + 1024;
    const int ar0 = o0 >> 6, ar1 = o1 >> 6;
    const int ac0 = (o0 & 63) >> 1, ac1 = (o1 & 63) >> 1;
    const size_t aof0 = (size_t)(m0 + ar0) * K + ac0;
    const size_t aof1 = (size_t)(m0 + ar1) * K + ac1;
    const size_t bof0 = (size_t)(n0 + ar0) * K + ac0;
    const size_t bof1 = (size_t)(n0 + ar1) * K + ac1;
    u16* dA0 = &As[w * 1024];       u16* dA1 = &As[w * 1024 + 512];
    u16* dB0 = &Bs[w * 1024];       u16* dB1 = &Bs[w * 1024 + 512];

    f32x4 acc[4][4] = {};

    for (int k0 = 0; k0 < K; k0 += 32) {
        GLDS16(A  + aof0 + k0, dA0);
        GLDS16(A  + aof1 + k0, dA1);
        GLDS16(Bm + bof0 + k0, dB0);
        GLDS16(Bm + bof1 + k0, dB1);
        __syncthreads();              // drains vmcnt -> staging visible
        s16x8 af[4], bf[4];
        #pragma unroll
        for (int i = 0; i < 4; ++i)
            af[i] = *reinterpret_cast<const s16x8*>(&As[(wm + i * 16 + lr) * 32 + lg * 8]);
        #pragma unroll
        for (int j = 0; j < 4; ++j)
            bf[j] = *reinterpret_cast<const s16x8*>(&Bs[(wn + j * 16 + lr) * 32 + lg * 8]);
        #pragma unroll
        for (int i = 0; i < 4; ++i)
            #pragma unroll
            for (int j = 0; j < 4; ++j)
                acc[i][j] = __builtin_amdgcn_mfma_f32_16x16x32_bf16(af[i], bf[j], acc[i][j], 0, 0, 0);
        __syncthreads();
    }

    #pragma unroll
    for (int i = 0; i < 4; ++i)
        #pragma unroll
        for (int j = 0; j < 4; ++j)
            #pragma unroll
            for (int r = 0; r < 4; ++r) {
                int m = m0 + wm + i * 16 + lg * 4 + r;
                int n = n0 + wn + j * 16 + lr;
                if constexpr (OUT_BF16)
                    reinterpret_cast<u16*>(Cout)[(size_t)m * N + n] = f2bf(acc[i][j][r]);
                else
                    reinterpret_cast<float*>(Cout)[(size_t)m * N + n] = acc[i][j][r];
            }
}

// ---------------- RoPE + scatter into Q (B,H,T,D), K (B,KVH,T,D), Vt (B,KVH,D,T) ----------------
__global__ void k_rope_scatter(const u16* __restrict__ qkv,
                               const float* __restrict__ fcos,
                               const float* __restrict__ fsin,
                               u16* __restrict__ Q,
                               u16* __restrict__ Kb,
                               u16* __restrict__ Vt) {
    int p = blockIdx.x * blockDim.x + threadIdx.x;       // pair index
    if (p >= MM * (QKVD / 2)) return;
    int row = p / (QKVD / 2);
    int f   = (p % (QKVD / 2)) * 2;
    int b = row / TT, t = row % TT;
    uint32_t pk = reinterpret_cast<const uint32_t*>(qkv)[(size_t)row * (QKVD / 2) + (f >> 1)];
    u16 u0 = (u16)(pk & 0xffff), u1 = (u16)(pk >> 16);
    if (f < NH * HD) {                       // Q with RoPE
        int h = f / HD, d = f % HD;
        float c = fcos[t * 32 + (d >> 1)], s = fsin[t * 32 + (d >> 1)];
        float x0 = bf2f(u0), x1 = bf2f(u1);
        uint32_t o = (uint32_t)f2bf(x0 * c - x1 * s) | ((uint32_t)f2bf(x0 * s + x1 * c) << 16);
        *reinterpret_cast<uint32_t*>(Q + ((size_t)((b * NH + h) * TT + t)) * HD + d) = o;
    } else if (f < NH * HD + NKV * HD) {     // K with RoPE
        int fk = f - NH * HD;
        int h = fk / HD, d = fk % HD;
        float c = fcos[t * 32 + (d >> 1)], s = fsin[t * 32 + (d >> 1)];
        float x0 = bf2f(u0), x1 = bf2f(u1);
        uint32_t o = (uint32_t)f2bf(x0 * c - x1 * s) | ((uint32_t)f2bf(x0 * s + x1 * c) << 16);
        *reinterpret_cast<uint32_t*>(Kb + ((size_t)((b * NKV + h) * TT + t)) * HD + d) = o;
    } else {                                 // V, transposed store (d-major)
        int fv = f - NH * HD - NKV * HD;
        int h = fv / HD, d = fv % HD;
        Vt[((size_t)(b * NKV + h) * HD + d) * TT + t]     = u0;
        Vt[((size_t)(b * NKV + h) * HD + d + 1) * TT + t] = u1;
    }
}

// ---------------- causal GQA flash attention ----------------
// grid (16, NH, B): block handles paired q-tiles {j, 31-j} (uniform 33 kv-tiles/block).
// 4 waves; wave w owns 16 q-rows of the 64-row tile. KVBLK=64.
// K/V double-buffered in LDS via global_load_lds (linear dest, XOR-pre-swizzled source),
// reads apply the same XOR -> conflict-free ds_read_b128. Counted vmcnt(4), raw s_barrier.
__global__ __launch_bounds__(256) void k_attn(const u16* __restrict__ Q,
                                              const u16* __restrict__ Kb,
                                              const u16* __restrict__ Vt,
                                              u16* __restrict__ Y) {
    __shared__ u16 Ks[2][4096];      // [kv 64][d 64] swizzled, 8192 B per buf
    __shared__ u16 Vs[2][4096];      // [d 64][kv 64] swizzled
    __shared__ u16 Ps[4][1024];      // per-wave P [q 16][kv 64] swizzled (2048 B)

    const int tid = threadIdx.x;
    const int w = tid >> 6, lane = tid & 63;
    const int lr = lane & 15, lg = lane >> 4;
    const int b = blockIdx.z, h = blockIdx.y, kvh = h >> 2;
    const float scale = 0.125f;      // 1/sqrt(64)

    const u16* qbase = Q  + ((size_t)(b * NH  + h  ) * TT) * HD;
    const u16* kbase = Kb + ((size_t)(b * NKV + kvh) * TT) * HD;
    const u16* vbase = Vt + ((size_t)(b * NKV + kvh) * HD) * TT;

    // staging thread-constants: linear dest byte o -> (row, swizzled col)
    const int o0 = w * 2048 + lane * 16, o1 = o0 + 1024;
    const int r0 = o0 >> 7, r1 = o1 >> 7;
    const int c0 = (o0 & 127) ^ ((r0 & 7) << 4);
    const int c1 = (o1 & 127) ^ ((r1 & 7) << 4);
    const size_t kof0 = (size_t)r0 * HD + (c0 >> 1);
    const size_t kof1 = (size_t)r1 * HD + (c1 >> 1);
    const size_t vof0 = (size_t)r0 * TT + (c0 >> 1);
    const size_t vof1 = (size_t)r1 * TT + (c1 >> 1);

    #pragma unroll
    for (int pi = 0; pi < 2; ++pi) {
        const int j   = pi ? (NTILE - 1 - (int)blockIdx.x) : (int)blockIdx.x;
        const int q0b = j * 64;
        const int q0w = q0b + w * 16;
        const int nt  = j + 1;               // kv tiles 0..j

        s16x8 aq0 = *reinterpret_cast<const s16x8*>(qbase + (size_t)(q0w + lr) * HD + lg * 8);
        s16x8 aq1 = *reinterpret_cast<const s16x8*>(qbase + (size_t)(q0w + lr) * HD + 32 + lg * 8);
        asm volatile("s_waitcnt vmcnt(0)" ::: "memory");   // only stage loads in vmcnt from here

        // prologue stage tile 0 into buf 0 (4 vm ops/thread: K,K,V,V)
        GLDS16(kbase + kof0, &Ks[0][w * 1024]);
        GLDS16(kbase + kof1, &Ks[0][w * 1024 + 512]);
        GLDS16(vbase + vof0, &Vs[0][w * 1024]);
        GLDS16(vbase + vof1, &Vs[0][w * 1024 + 512]);

        float mrow[4] = {-1e30f, -1e30f, -1e30f, -1e30f};
        float lrow[4] = {0.f, 0.f, 0.f, 0.f};
        f32x4 oacc[4] = {};

        for (int t = 0; t < nt; ++t) {
            const int cur = t & 1;
            const int kv0 = t * 64;
            if (t + 1 < nt) {
                const size_t kb2 = (size_t)(kv0 + 64) * HD;
                GLDS16(kbase + kb2 + kof0, &Ks[cur ^ 1][w * 1024]);
                GLDS16(kbase + kb2 + kof1, &Ks[cur ^ 1][w * 1024 + 512]);
                GLDS16(vbase + (kv0 + 64) + vof0, &Vs[cur ^ 1][w * 1024]);
                GLDS16(vbase + (kv0 + 64) + vof1, &Vs[cur ^ 1][w * 1024 + 512]);
                asm volatile("s_waitcnt vmcnt(4)" ::: "memory");   // tile t resident, t+1 in flight
            } else {
                asm volatile("s_waitcnt vmcnt(0)" ::: "memory");
            }
            __builtin_amdgcn_s_barrier();
            __builtin_amdgcn_sched_barrier(0);

            const char* Kl = (const char*)&Ks[cur][0];
            const char* Vl = (const char*)&Vs[cur][0];
            char*       Pw = (char*)&Ps[w][0];

            // QK^T: 4 kv sub-tiles of 16
            f32x4 sc[4];
            #pragma unroll
            for (int u = 0; u < 4; ++u) {
                const int row = u * 16 + lr;
                const int x = (row & 7) << 4;
                s16x8 b0 = *reinterpret_cast<const s16x8*>(Kl + row * 128 + ((lg * 16) ^ x));
                s16x8 b1 = *reinterpret_cast<const s16x8*>(Kl + row * 128 + ((64 + lg * 16) ^ x));
                f32x4 a = {};
                a = __builtin_amdgcn_mfma_f32_16x16x32_bf16(aq0, b0, a, 0, 0, 0);
                a = __builtin_amdgcn_mfma_f32_16x16x32_bf16(aq1, b1, a, 0, 0, 0);
                sc[u] = a;
            }

            // online softmax (16-lane butterflies)
            float pv[4][4], tmax[4], tsum[4], alpha[4];
            #pragma unroll
            for (int r = 0; r < 4; ++r) {
                const int qrow = q0w + lg * 4 + r;
                float mv = -1e30f;
                #pragma unroll
                for (int u = 0; u < 4; ++u) {
                    float vv = (kv0 + u * 16 + lr <= qrow) ? sc[u][r] * scale : -1e30f;
                    pv[u][r] = vv;
                    mv = fmaxf(mv, vv);
                }
                tmax[r] = mv;
            }
            #pragma unroll
            for (int d = 1; d < 16; d <<= 1)
                #pragma unroll
                for (int r = 0; r < 4; ++r)
                    tmax[r] = fmaxf(tmax[r], __shfl_xor(tmax[r], d, 64));
            #pragma unroll
            for (int r = 0; r < 4; ++r) {
                float mn = fmaxf(mrow[r], tmax[r]);
                alpha[r] = __expf(mrow[r] - mn);
                mrow[r] = mn;
                float ts = 0.f;
                #pragma unroll
                for (int u = 0; u < 4; ++u) {
                    float e = __expf(pv[u][r] - mn);
                    pv[u][r] = e;
                    ts += e;
                }
                tsum[r] = ts;
            }
            #pragma unroll
            for (int d = 1; d < 16; d <<= 1)
                #pragma unroll
                for (int r = 0; r < 4; ++r)
                    tsum[r] += __shfl_xor(tsum[r], d, 64);
            #pragma unroll
            for (int r = 0; r < 4; ++r) lrow[r] = lrow[r] * alpha[r] + tsum[r];
            #pragma unroll
            for (int db = 0; db < 4; ++db)
                #pragma unroll
                for (int r = 0; r < 4; ++r)
                    oacc[db][r] *= alpha[r];

            // P -> LDS (swizzled) -> A-fragments
            #pragma unroll
            for (int u = 0; u < 4; ++u)
                #pragma unroll
                for (int r = 0; r < 4; ++r) {
                    const int q = lg * 4 + r;
                    const int cb = (u * 16 + lr) * 2;
                    *reinterpret_cast<u16*>(Pw + q * 128 + (cb ^ ((q & 7) << 4))) = f2bf(pv[u][r]);
                }
            asm volatile("s_waitcnt lgkmcnt(0)" ::: "memory");
            __builtin_amdgcn_sched_barrier(0);
            const int xp = (lr & 7) << 4;
            s16x8 pa0 = *reinterpret_cast<const s16x8*>(Pw + lr * 128 + ((lg * 16) ^ xp));
            s16x8 pa1 = *reinterpret_cast<const s16x8*>(Pw + lr * 128 + ((64 + lg * 16) ^ xp));

            // PV
            #pragma unroll
            for (int db = 0; db < 4; ++db) {
                const int vr = db * 16 + lr;
                const int x = (vr & 7) << 4;
                s16x8 v0 = *reinterpret_cast<const s16x8*>(Vl + vr * 128 + ((lg * 16) ^ x));
                s16x8 v1 = *reinterpret_cast<const s16x8*>(Vl + vr * 128 + ((64 + lg * 16) ^ x));
                oacc[db] = __builtin_amdgcn_mfma_f32_16x16x32_bf16(pa0, v0, oacc[db], 0, 0, 0);
                oacc[db] = __builtin_amdgcn_mfma_f32_16x16x32_bf16(pa1, v1, oacc[db], 0, 0, 0);
            }

            __builtin_amdgcn_sched_barrier(0);
            __builtin_amdgcn_s_barrier();
        }

        // epilogue
        float rinv[4];
        #pragma unroll
        for (int r = 0; r < 4; ++r) rinv[r] = 1.f / lrow[r];
        #pragma unroll
        for (int db = 0; db < 4; ++db)
            #pragma unroll
            for (int r = 0; r < 4; ++r) {
                const int t = q0w + lg * 4 + r;
                Y[((size_t)(b * TT + t) * NH + h) * HD + db * 16 + lr] = f2bf(oacc[db][r] * rinv[r]);
            }
    }
}

// ---------------- launch ----------------
extern "C" void kernel_launch(void* const* d_in, const int* in_sizes, int n_in,
                              void* d_out, int out_size, void* d_ws, size_t ws_size,
                              hipStream_t stream) {
    (void)in_sizes; (void)n_in; (void)out_size; (void)ws_size;
    const float* x     = (const float*)d_in[0];
    const float* wqkv  = (const float*)d_in[1];
    const float* wproj = (const float*)d_in[2];
    const float* fcos  = (const float*)d_in[3];
    const float* fsin  = (const float*)d_in[4];

    char* ws = (char*)d_ws;
    size_t off = 0;
    auto alloc = [&](size_t bytes) { void* p = ws + off; off += (bytes + 255) & ~(size_t)255; return p; };
    u16* Xbf  = (u16*)alloc((size_t)MM * CE * 2);
    u16* Wqb  = (u16*)alloc((size_t)QKVD * CE * 2);
    u16* Wpb  = (u16*)alloc((size_t)CE * CE * 2);
    u16* QKVb = (u16*)alloc((size_t)MM * QKVD * 2);
    u16* Qb   = (u16*)alloc((size_t)BB * NH * TT * HD * 2);
    u16* Kbuf = (u16*)alloc((size_t)BB * NKV * TT * HD * 2);
    u16* Vtb  = (u16*)alloc((size_t)BB * NKV * HD * TT * 2);
    u16* Yb   = (u16*)alloc((size_t)MM * CE * 2);

    k_f32_to_bf16<<<(MM * CE / 8 + 255) / 256, 256, 0, stream>>>(x, Xbf, MM * CE / 8);
    k_f32_to_bf16<<<(QKVD * CE / 8 + 255) / 256, 256, 0, stream>>>(wqkv, Wqb, QKVD * CE / 8);
    k_f32_to_bf16<<<(CE * CE / 8 + 255) / 256, 256, 0, stream>>>(wproj, Wpb, CE * CE / 8);

    dim3 g1(QKVD / 128, MM / 128);
    k_gemm_bt<true><<<g1, 256, 0, stream>>>(Xbf, Wqb, QKVb, MM, QKVD, CE);

    int pairs = MM * (QKVD / 2);
    k_rope_scatter<<<(pairs + 255) / 256, 256, 0, stream>>>(QKVb, fcos, fsin, Qb, Kbuf, Vtb);

    dim3 ga(NTILE / 2, NH, BB);
    k_attn<<<ga, 256, 0, stream>>>(Qb, Kbuf, Vtb, Yb);

    dim3 g2(CE / 128, MM / 128);
    k_gemm_bt<false><<<g2, 256, 0, stream>>>(Yb, Wpb, d_out, MM, CE, CE);
}

// Round 3
// 294.424 us; speedup vs baseline: 2.0928x; 1.0050x over previous
//
#include <hip/hip_runtime.h>
#include <hip/hip_bf16.h>
#include <cstdint>

#define NH   32
#define NKV  8
#define HD   64
#define CE   2048      // n_embd
#define BB   2
#define TT   2048
#define QKVD 3072      // (32 + 2*8) * 64
#define MM   (BB*TT)   // 4096 rows
#define NTILE (TT/64)  // 32 q-tiles of 64

typedef float  f32x4 __attribute__((ext_vector_type(4)));
typedef short  s16x8 __attribute__((ext_vector_type(8)));
typedef unsigned short u16;

#define AS1 __attribute__((address_space(1)))
#define AS3 __attribute__((address_space(3)))
#define GLDS16(src, dst) __builtin_amdgcn_global_load_lds( \
    (const AS1 uint32_t*)(src), (AS3 uint32_t*)(dst), 16, 0, 0)

static __device__ __forceinline__ float bf2f(u16 u) {
    union { uint32_t u; float f; } v; v.u = ((uint32_t)u) << 16; return v.f;
}
static __device__ __forceinline__ u16 f2bf(float f) {
    union { float f; uint32_t u; } v; v.f = f;
    uint32_t r = v.u + 0x7fffu + ((v.u >> 16) & 1u);   // RNE
    return (u16)(r >> 16);
}
static __device__ __forceinline__ uint32_t cvtpk(float lo, float hi) {
    uint32_t r;
    asm("v_cvt_pk_bf16_f32 %0, %1, %2" : "=v"(r) : "v"(lo), "v"(hi));
    return r;
}

// ---------------- fp32 -> bf16 convert (vectorized 8/thread, cvt_pk) ----------------
__global__ void k_f32_to_bf16(const float* __restrict__ in, uint32_t* __restrict__ out, int n8) {
    int i = blockIdx.x * blockDim.x + threadIdx.x;
    if (i >= n8) return;
    const float4* p = reinterpret_cast<const float4*>(in) + (size_t)i * 2;
    float4 a = p[0], b = p[1];
    uint4 o;
    o.x = cvtpk(a.x, a.y); o.y = cvtpk(a.z, a.w);
    o.z = cvtpk(b.x, b.y); o.w = cvtpk(b.z, b.w);
    *reinterpret_cast<uint4*>(out + (size_t)i * 4) = o;
}

// ---------------- bf16 GEMM (m97 structure): C(M,N) = A(M,K) @ B(N,K)^T ----------------
template<bool OUT_BF16>
__global__ __launch_bounds__(256) void k_gemm_bt(const u16* __restrict__ A,
                                                 const u16* __restrict__ Bm,
                                                 void* __restrict__ Cout,
                                                 int M, int N, int K) {
    __shared__ u16 As[128 * 32];
    __shared__ u16 Bs[128 * 32];
    const int tid  = threadIdx.x;
    const int m0   = blockIdx.y * 128;
    const int n0   = blockIdx.x * 128;
    const int w    = tid >> 6;
    const int lane = tid & 63;
    const int lr   = lane & 15, lg = lane >> 4;
    const int wm   = (w >> 1) * 64, wn = (w & 1) * 64;

    const int o0 = w * 2048 + lane * 16, o1 = o0 + 1024;
    const int ar0 = o0 >> 6, ar1 = o1 >> 6;
    const int ac0 = (o0 & 63) >> 1, ac1 = (o1 & 63) >> 1;
    const size_t aof0 = (size_t)(m0 + ar0) * K + ac0;
    const size_t aof1 = (size_t)(m0 + ar1) * K + ac1;
    const size_t bof0 = (size_t)(n0 + ar0) * K + ac0;
    const size_t bof1 = (size_t)(n0 + ar1) * K + ac1;
    u16* dA0 = &As[w * 1024];       u16* dA1 = &As[w * 1024 + 512];
    u16* dB0 = &Bs[w * 1024];       u16* dB1 = &Bs[w * 1024 + 512];

    f32x4 acc[4][4] = {};

    for (int k0 = 0; k0 < K; k0 += 32) {
        GLDS16(A  + aof0 + k0, dA0);
        GLDS16(A  + aof1 + k0, dA1);
        GLDS16(Bm + bof0 + k0, dB0);
        GLDS16(Bm + bof1 + k0, dB1);
        __syncthreads();
        s16x8 af[4], bf[4];
        #pragma unroll
        for (int i = 0; i < 4; ++i)
            af[i] = *reinterpret_cast<const s16x8*>(&As[(wm + i * 16 + lr) * 32 + lg * 8]);
        #pragma unroll
        for (int j = 0; j < 4; ++j)
            bf[j] = *reinterpret_cast<const s16x8*>(&Bs[(wn + j * 16 + lr) * 32 + lg * 8]);
        #pragma unroll
        for (int i = 0; i < 4; ++i)
            #pragma unroll
            for (int j = 0; j < 4; ++j)
                acc[i][j] = __builtin_amdgcn_mfma_f32_16x16x32_bf16(af[i], bf[j], acc[i][j], 0, 0, 0);
        __syncthreads();
    }

    #pragma unroll
    for (int i = 0; i < 4; ++i)
        #pragma unroll
        for (int j = 0; j < 4; ++j)
            #pragma unroll
            for (int r = 0; r < 4; ++r) {
                int m = m0 + wm + i * 16 + lg * 4 + r;
                int n = n0 + wn + j * 16 + lr;
                if constexpr (OUT_BF16)
                    reinterpret_cast<u16*>(Cout)[(size_t)m * N + n] = f2bf(acc[i][j][r]);
                else
                    reinterpret_cast<float*>(Cout)[(size_t)m * N + n] = acc[i][j][r];
            }
}

// ---------------- RoPE + scatter into Q (B,H,T,D), K (B,KVH,T,D), Vt (B,KVH,D,T) ----------------
__global__ void k_rope_scatter(const u16* __restrict__ qkv,
                               const float* __restrict__ fcos,
                               const float* __restrict__ fsin,
                               u16* __restrict__ Q,
                               u16* __restrict__ Kb,
                               u16* __restrict__ Vt) {
    int p = blockIdx.x * blockDim.x + threadIdx.x;       // pair index
    if (p >= MM * (QKVD / 2)) return;
    int row = p / (QKVD / 2);
    int f   = (p % (QKVD / 2)) * 2;
    int b = row / TT, t = row % TT;
    uint32_t pk = reinterpret_cast<const uint32_t*>(qkv)[(size_t)row * (QKVD / 2) + (f >> 1)];
    u16 u0 = (u16)(pk & 0xffff), u1 = (u16)(pk >> 16);
    if (f < NH * HD) {                       // Q with RoPE
        int h = f / HD, d = f % HD;
        float c = fcos[t * 32 + (d >> 1)], s = fsin[t * 32 + (d >> 1)];
        float x0 = bf2f(u0), x1 = bf2f(u1);
        uint32_t o = cvtpk(x0 * c - x1 * s, x0 * s + x1 * c);
        *reinterpret_cast<uint32_t*>(Q + ((size_t)((b * NH + h) * TT + t)) * HD + d) = o;
    } else if (f < NH * HD + NKV * HD) {     // K with RoPE
        int fk = f - NH * HD;
        int h = fk / HD, d = fk % HD;
        float c = fcos[t * 32 + (d >> 1)], s = fsin[t * 32 + (d >> 1)];
        float x0 = bf2f(u0), x1 = bf2f(u1);
        uint32_t o = cvtpk(x0 * c - x1 * s, x0 * s + x1 * c);
        *reinterpret_cast<uint32_t*>(Kb + ((size_t)((b * NKV + h) * TT + t)) * HD + d) = o;
    } else {                                 // V, transposed store (d-major)
        int fv = f - NH * HD - NKV * HD;
        int h = fv / HD, d = fv % HD;
        Vt[((size_t)(b * NKV + h) * HD + d) * TT + t]     = u0;
        Vt[((size_t)(b * NKV + h) * HD + d + 1) * TT + t] = u1;
    }
}

// ---------------- causal GQA flash attention ----------------
// grid (32, NH, B), j = 31-bx (heavy blocks dispatch first), 4 blocks/CU.
// 4 waves; wave w owns 16 q-rows. KVBLK=64, double-buffered LDS (swizzled via
// pre-swizzled global source). Defer-max online softmax: common path has NO
// cross-lane reduces (per-lane partial row-sum, reduced once at end).
__global__ __launch_bounds__(256) void k_attn(const u16* __restrict__ Q,
                                              const u16* __restrict__ Kb,
                                              const u16* __restrict__ Vt,
                                              u16* __restrict__ Y) {
    __shared__ u16 Ks[2][4096];      // [kv 64][d 64] swizzled
    __shared__ u16 Vs[2][4096];      // [d 64][kv 64] swizzled
    __shared__ u16 Ps[4][1024];      // per-wave P [q 16][kv 64] swizzled

    const int tid = threadIdx.x;
    const int w = tid >> 6, lane = tid & 63;
    const int lr = lane & 15, lg = lane >> 4;
    const int b = blockIdx.z, h = blockIdx.y, kvh = h >> 2;
    const float scale2 = 0.18033688011112042f;   // (1/8) * log2(e)

    const u16* qbase = Q  + ((size_t)(b * NH  + h  ) * TT) * HD;
    const u16* kbase = Kb + ((size_t)(b * NKV + kvh) * TT) * HD;
    const u16* vbase = Vt + ((size_t)(b * NKV + kvh) * HD) * TT;

    const int o0 = w * 2048 + lane * 16, o1 = o0 + 1024;
    const int r0 = o0 >> 7, r1 = o1 >> 7;
    const int c0 = (o0 & 127) ^ ((r0 & 7) << 4);
    const int c1 = (o1 & 127) ^ ((r1 & 7) << 4);
    const size_t kof0 = (size_t)r0 * HD + (c0 >> 1);
    const size_t kof1 = (size_t)r1 * HD + (c1 >> 1);
    const size_t vof0 = (size_t)r0 * TT + (c0 >> 1);
    const size_t vof1 = (size_t)r1 * TT + (c1 >> 1);

    const int j   = NTILE - 1 - (int)blockIdx.x;
    const int q0w = j * 64 + w * 16;
    const int nt  = j + 1;

    s16x8 aq0 = *reinterpret_cast<const s16x8*>(qbase + (size_t)(q0w + lr) * HD + lg * 8);
    s16x8 aq1 = *reinterpret_cast<const s16x8*>(qbase + (size_t)(q0w + lr) * HD + 32 + lg * 8);
    asm volatile("s_waitcnt vmcnt(0)" ::: "memory");   // only stage loads in vmcnt from here

    GLDS16(kbase + kof0, &Ks[0][w * 1024]);
    GLDS16(kbase + kof1, &Ks[0][w * 1024 + 512]);
    GLDS16(vbase + vof0, &Vs[0][w * 1024]);
    GLDS16(vbase + vof1, &Vs[0][w * 1024 + 512]);

    float mrow[4]  = {-1e30f, -1e30f, -1e30f, -1e30f};
    float lrowp[4] = {0.f, 0.f, 0.f, 0.f};        // per-lane PARTIAL row sums
    f32x4 oacc[4] = {};

    for (int t = 0; t < nt; ++t) {
        const int cur = t & 1;
        const int kv0 = t * 64;
        if (t + 1 < nt) {
            const size_t kb2 = (size_t)(kv0 + 64) * HD;
            GLDS16(kbase + kb2 + kof0, &Ks[cur ^ 1][w * 1024]);
            GLDS16(kbase + kb2 + kof1, &Ks[cur ^ 1][w * 1024 + 512]);
            GLDS16(vbase + (kv0 + 64) + vof0, &Vs[cur ^ 1][w * 1024]);
            GLDS16(vbase + (kv0 + 64) + vof1, &Vs[cur ^ 1][w * 1024 + 512]);
            asm volatile("s_waitcnt vmcnt(4)" ::: "memory");
        } else {
            asm volatile("s_waitcnt vmcnt(0)" ::: "memory");
        }
        __builtin_amdgcn_s_barrier();
        __builtin_amdgcn_sched_barrier(0);

        const char* Kl = (const char*)&Ks[cur][0];
        const char* Vl = (const char*)&Vs[cur][0];
        char*       Pw = (char*)&Ps[w][0];

        // QK^T: 4 kv sub-tiles of 16
        f32x4 sc[4];
        #pragma unroll
        for (int u = 0; u < 4; ++u) {
            const int row = u * 16 + lr;
            const int x = (row & 7) << 4;
            s16x8 b0 = *reinterpret_cast<const s16x8*>(Kl + row * 128 + ((lg * 16) ^ x));
            s16x8 b1 = *reinterpret_cast<const s16x8*>(Kl + row * 128 + ((64 + lg * 16) ^ x));
            f32x4 a = {};
            a = __builtin_amdgcn_mfma_f32_16x16x32_bf16(aq0, b0, a, 0, 0, 0);
            a = __builtin_amdgcn_mfma_f32_16x16x32_bf16(aq1, b1, a, 0, 0, 0);
            sc[u] = a;
        }

        // scores in exp2 domain (+ causal mask only on the diagonal tile)
        float sv[4][4];
        const bool needmask = (kv0 + 63 > q0w);
        if (needmask) {
            #pragma unroll
            for (int r = 0; r < 4; ++r) {
                const int dq = q0w - kv0 + lg * 4 + r;
                #pragma unroll
                for (int u = 0; u < 4; ++u)
                    sv[u][r] = (u * 16 + lr <= dq) ? sc[u][r] * scale2 : -1e30f;
            }
        } else {
            #pragma unroll
            for (int u = 0; u < 4; ++u)
                #pragma unroll
                for (int r = 0; r < 4; ++r)
                    sv[u][r] = sc[u][r] * scale2;
        }

        // defer-max check: per-lane max only, one ballot, no butterflies
        float tmax[4];
        #pragma unroll
        for (int r = 0; r < 4; ++r)
            tmax[r] = fmaxf(fmaxf(sv[0][r], sv[1][r]), fmaxf(sv[2][r], sv[3][r]));
        bool ex = false;
        #pragma unroll
        for (int r = 0; r < 4; ++r) ex = ex || (tmax[r] > mrow[r] + 8.f);
        if (__any(ex)) {                      // rare rescale path
            #pragma unroll
            for (int d = 1; d < 16; d <<= 1)
                #pragma unroll
                for (int r = 0; r < 4; ++r)
                    tmax[r] = fmaxf(tmax[r], __shfl_xor(tmax[r], d, 64));
            #pragma unroll
            for (int r = 0; r < 4; ++r) {
                float mn = fmaxf(mrow[r], tmax[r]);
                float alpha = __builtin_amdgcn_exp2f(mrow[r] - mn);
                mrow[r] = mn;
                lrowp[r] *= alpha;
                #pragma unroll
                for (int db = 0; db < 4; ++db) oacc[db][r] *= alpha;
            }
        }

        // P = exp2(sv - mrow); accumulate per-lane partial row sums
        float pv[4][4];
        #pragma unroll
        for (int u = 0; u < 4; ++u)
            #pragma unroll
            for (int r = 0; r < 4; ++r)
                pv[u][r] = __builtin_amdgcn_exp2f(sv[u][r] - mrow[r]);
        #pragma unroll
        for (int r = 0; r < 4; ++r)
            lrowp[r] += (pv[0][r] + pv[1][r]) + (pv[2][r] + pv[3][r]);

        // P -> LDS (swizzled, cvt_pk pairs over adjacent q rows)
        #pragma unroll
        for (int u = 0; u < 4; ++u) {
            uint32_t p01 = cvtpk(pv[u][0], pv[u][1]);
            uint32_t p23 = cvtpk(pv[u][2], pv[u][3]);
            const int cb = (u * 16 + lr) * 2;
            const int q0 = lg * 4;
            *reinterpret_cast<u16*>(Pw + (q0    ) * 128 + (cb ^ (((q0    ) & 7) << 4))) = (u16)(p01 & 0xffff);
            *reinterpret_cast<u16*>(Pw + (q0 + 1) * 128 + (cb ^ (((q0 + 1) & 7) << 4))) = (u16)(p01 >> 16);
            *reinterpret_cast<u16*>(Pw + (q0 + 2) * 128 + (cb ^ (((q0 + 2) & 7) << 4))) = (u16)(p23 & 0xffff);
            *reinterpret_cast<u16*>(Pw + (q0 + 3) * 128 + (cb ^ (((q0 + 3) & 7) << 4))) = (u16)(p23 >> 16);
        }
        asm volatile("s_waitcnt lgkmcnt(0)" ::: "memory");
        __builtin_amdgcn_sched_barrier(0);
        const int xp = (lr & 7) << 4;
        s16x8 pa0 = *reinterpret_cast<const s16x8*>(Pw + lr * 128 + ((lg * 16) ^ xp));
        s16x8 pa1 = *reinterpret_cast<const s16x8*>(Pw + lr * 128 + ((64 + lg * 16) ^ xp));

        // PV
        #pragma unroll
        for (int db = 0; db < 4; ++db) {
            const int vr = db * 16 + lr;
            const int x = (vr & 7) << 4;
            s16x8 v0 = *reinterpret_cast<const s16x8*>(Vl + vr * 128 + ((lg * 16) ^ x));
            s16x8 v1 = *reinterpret_cast<const s16x8*>(Vl + vr * 128 + ((64 + lg * 16) ^ x));
            oacc[db] = __builtin_amdgcn_mfma_f32_16x16x32_bf16(pa0, v0, oacc[db], 0, 0, 0);
            oacc[db] = __builtin_amdgcn_mfma_f32_16x16x32_bf16(pa1, v1, oacc[db], 0, 0, 0);
        }

        __builtin_amdgcn_sched_barrier(0);
        __builtin_amdgcn_s_barrier();
    }

    // final row-sum reduce (once per block, not per tile)
    #pragma unroll
    for (int d = 1; d < 16; d <<= 1)
        #pragma unroll
        for (int r = 0; r < 4; ++r)
            lrowp[r] += __shfl_xor(lrowp[r], d, 64);
    float rinv[4];
    #pragma unroll
    for (int r = 0; r < 4; ++r) rinv[r] = 1.f / lrowp[r];
    #pragma unroll
    for (int db = 0; db < 4; ++db)
        #pragma unroll
        for (int r = 0; r < 4; ++r) {
            const int t = q0w + lg * 4 + r;
            Y[((size_t)(b * TT + t) * NH + h) * HD + db * 16 + lr] = f2bf(oacc[db][r] * rinv[r]);
        }
}

// ---------------- launch ----------------
extern "C" void kernel_launch(void* const* d_in, const int* in_sizes, int n_in,
                              void* d_out, int out_size, void* d_ws, size_t ws_size,
                              hipStream_t stream) {
    (void)in_sizes; (void)n_in; (void)out_size; (void)ws_size;
    const float* x     = (const float*)d_in[0];
    const float* wqkv  = (const float*)d_in[1];
    const float* wproj = (const float*)d_in[2];
    const float* fcos  = (const float*)d_in[3];
    const float* fsin  = (const float*)d_in[4];

    char* ws = (char*)d_ws;
    size_t off = 0;
    auto alloc = [&](size_t bytes) { void* p = ws + off; off += (bytes + 255) & ~(size_t)255; return p; };
    u16* Xbf  = (u16*)alloc((size_t)MM * CE * 2);
    u16* Wqb  = (u16*)alloc((size_t)QKVD * CE * 2);
    u16* Wpb  = (u16*)alloc((size_t)CE * CE * 2);
    u16* QKVb = (u16*)alloc((size_t)MM * QKVD * 2);
    u16* Qb   = (u16*)alloc((size_t)BB * NH * TT * HD * 2);
    u16* Kbuf = (u16*)alloc((size_t)BB * NKV * TT * HD * 2);
    u16* Vtb  = (u16*)alloc((size_t)BB * NKV * HD * TT * 2);
    u16* Yb   = (u16*)alloc((size_t)MM * CE * 2);

    k_f32_to_bf16<<<(MM * CE / 8 + 255) / 256, 256, 0, stream>>>(x, (uint32_t*)Xbf, MM * CE / 8);
    k_f32_to_bf16<<<(QKVD * CE / 8 + 255) / 256, 256, 0, stream>>>(wqkv, (uint32_t*)Wqb, QKVD * CE / 8);
    k_f32_to_bf16<<<(CE * CE / 8 + 255) / 256, 256, 0, stream>>>(wproj, (uint32_t*)Wpb, CE * CE / 8);

    dim3 g1(QKVD / 128, MM / 128);
    k_gemm_bt<true><<<g1, 256, 0, stream>>>(Xbf, Wqb, QKVb, MM, QKVD, CE);

    int pairs = MM * (QKVD / 2);
    k_rope_scatter<<<(pairs + 255) / 256, 256, 0, stream>>>(QKVb, fcos, fsin, Qb, Kbuf, Vtb);

    dim3 ga(NTILE, NH, BB);
    k_attn<<<ga, 256, 0, stream>>>(Qb, Kbuf, Vtb, Yb);

    dim3 g2(CE / 128, MM / 128);
    k_gemm_bt<false><<<g2, 256, 0, stream>>>(Yb, Wpb, d_out, MM, CE, CE);
}

// Round 4
// 286.470 us; speedup vs baseline: 2.1509x; 1.0278x over previous
//
#include <hip/hip_runtime.h>
#include <hip/hip_bf16.h>
#include <cstdint>

#define NH   32
#define NKV  8
#define HD   64
#define CE   2048      // n_embd
#define BB   2
#define TT   2048
#define QKVD 3072      // (32 + 2*8) * 64
#define MM   (BB*TT)   // 4096 rows

typedef float  f32x4  __attribute__((ext_vector_type(4)));
typedef float  f32x16 __attribute__((ext_vector_type(16)));
typedef short  s16x8  __attribute__((ext_vector_type(8)));
typedef unsigned short u16;

#define AS1 __attribute__((address_space(1)))
#define AS3 __attribute__((address_space(3)))
#define GLDS16(src, dst) __builtin_amdgcn_global_load_lds( \
    (const AS1 uint32_t*)(src), (AS3 uint32_t*)(dst), 16, 0, 0)

static __device__ __forceinline__ float bf2f(u16 u) {
    union { uint32_t u; float f; } v; v.u = ((uint32_t)u) << 16; return v.f;
}
static __device__ __forceinline__ u16 f2bf(float f) {
    union { float f; uint32_t u; } v; v.f = f;
    uint32_t r = v.u + 0x7fffu + ((v.u >> 16) & 1u);   // RNE
    return (u16)(r >> 16);
}
static __device__ __forceinline__ uint32_t cvtpk(float lo, float hi) {
    uint32_t r;
    asm("v_cvt_pk_bf16_f32 %0, %1, %2" : "=v"(r) : "v"(lo), "v"(hi));
    return r;
}
// v_permlane32_swap_b32: a.hi32lanes <-> b.lo32lanes (both modified)
static __device__ __forceinline__ void plswap(uint32_t &a, uint32_t &b) {
    asm volatile("v_permlane32_swap_b32 %0, %1" : "+v"(a), "+v"(b));
}

// ---------------- fp32 -> bf16 convert (vectorized 8/thread, cvt_pk) ----------------
__global__ void k_f32_to_bf16(const float* __restrict__ in, uint32_t* __restrict__ out, int n8) {
    int i = blockIdx.x * blockDim.x + threadIdx.x;
    if (i >= n8) return;
    const float4* p = reinterpret_cast<const float4*>(in) + (size_t)i * 2;
    float4 a = p[0], b = p[1];
    uint4 o;
    o.x = cvtpk(a.x, a.y); o.y = cvtpk(a.z, a.w);
    o.z = cvtpk(b.x, b.y); o.w = cvtpk(b.z, b.w);
    *reinterpret_cast<uint4*>(out + (size_t)i * 4) = o;
}

// ---------------- bf16 GEMM (m97 structure): C(M,N) = A(M,K) @ B(N,K)^T ----------------
template<bool OUT_BF16>
__global__ __launch_bounds__(256) void k_gemm_bt(const u16* __restrict__ A,
                                                 const u16* __restrict__ Bm,
                                                 void* __restrict__ Cout,
                                                 int M, int N, int K) {
    __shared__ u16 As[128 * 32];
    __shared__ u16 Bs[128 * 32];
    const int tid  = threadIdx.x;
    const int m0   = blockIdx.y * 128;
    const int n0   = blockIdx.x * 128;
    const int w    = tid >> 6;
    const int lane = tid & 63;
    const int lr   = lane & 15, lg = lane >> 4;
    const int wm   = (w >> 1) * 64, wn = (w & 1) * 64;

    const int o0 = w * 2048 + lane * 16, o1 = o0 + 1024;
    const int ar0 = o0 >> 6, ar1 = o1 >> 6;
    const int ac0 = (o0 & 63) >> 1, ac1 = (o1 & 63) >> 1;
    const size_t aof0 = (size_t)(m0 + ar0) * K + ac0;
    const size_t aof1 = (size_t)(m0 + ar1) * K + ac1;
    const size_t bof0 = (size_t)(n0 + ar0) * K + ac0;
    const size_t bof1 = (size_t)(n0 + ar1) * K + ac1;
    u16* dA0 = &As[w * 1024];       u16* dA1 = &As[w * 1024 + 512];
    u16* dB0 = &Bs[w * 1024];       u16* dB1 = &Bs[w * 1024 + 512];

    f32x4 acc[4][4] = {};

    for (int k0 = 0; k0 < K; k0 += 32) {
        GLDS16(A  + aof0 + k0, dA0);
        GLDS16(A  + aof1 + k0, dA1);
        GLDS16(Bm + bof0 + k0, dB0);
        GLDS16(Bm + bof1 + k0, dB1);
        __syncthreads();
        s16x8 af[4], bf[4];
        #pragma unroll
        for (int i = 0; i < 4; ++i)
            af[i] = *reinterpret_cast<const s16x8*>(&As[(wm + i * 16 + lr) * 32 + lg * 8]);
        #pragma unroll
        for (int j = 0; j < 4; ++j)
            bf[j] = *reinterpret_cast<const s16x8*>(&Bs[(wn + j * 16 + lr) * 32 + lg * 8]);
        #pragma unroll
        for (int i = 0; i < 4; ++i)
            #pragma unroll
            for (int j = 0; j < 4; ++j)
                acc[i][j] = __builtin_amdgcn_mfma_f32_16x16x32_bf16(af[i], bf[j], acc[i][j], 0, 0, 0);
        __syncthreads();
    }

    #pragma unroll
    for (int i = 0; i < 4; ++i)
        #pragma unroll
        for (int j = 0; j < 4; ++j)
            #pragma unroll
            for (int r = 0; r < 4; ++r) {
                int m = m0 + wm + i * 16 + lg * 4 + r;
                int n = n0 + wn + j * 16 + lr;
                if constexpr (OUT_BF16)
                    reinterpret_cast<u16*>(Cout)[(size_t)m * N + n] = f2bf(acc[i][j][r]);
                else
                    reinterpret_cast<float*>(Cout)[(size_t)m * N + n] = acc[i][j][r];
            }
}

// ---------------- RoPE + scatter. Q gets scale*log2e folded in. ----------------
__global__ void k_rope_scatter(const u16* __restrict__ qkv,
                               const float* __restrict__ fcos,
                               const float* __restrict__ fsin,
                               u16* __restrict__ Q,
                               u16* __restrict__ Kb,
                               u16* __restrict__ Vt) {
    int p = blockIdx.x * blockDim.x + threadIdx.x;       // pair index
    if (p >= MM * (QKVD / 2)) return;
    int row = p / (QKVD / 2);
    int f   = (p % (QKVD / 2)) * 2;
    int b = row / TT, t = row % TT;
    uint32_t pk = reinterpret_cast<const uint32_t*>(qkv)[(size_t)row * (QKVD / 2) + (f >> 1)];
    u16 u0 = (u16)(pk & 0xffff), u1 = (u16)(pk >> 16);
    const float QS = 0.18033688011112042f;   // (1/sqrt(64)) * log2(e)
    if (f < NH * HD) {                       // Q with RoPE + folded softmax scale
        int h = f / HD, d = f % HD;
        float c = fcos[t * 32 + (d >> 1)], s = fsin[t * 32 + (d >> 1)];
        float x0 = bf2f(u0), x1 = bf2f(u1);
        uint32_t o = cvtpk((x0 * c - x1 * s) * QS, (x0 * s + x1 * c) * QS);
        *reinterpret_cast<uint32_t*>(Q + ((size_t)((b * NH + h) * TT + t)) * HD + d) = o;
    } else if (f < NH * HD + NKV * HD) {     // K with RoPE
        int fk = f - NH * HD;
        int h = fk / HD, d = fk % HD;
        float c = fcos[t * 32 + (d >> 1)], s = fsin[t * 32 + (d >> 1)];
        float x0 = bf2f(u0), x1 = bf2f(u1);
        uint32_t o = cvtpk(x0 * c - x1 * s, x0 * s + x1 * c);
        *reinterpret_cast<uint32_t*>(Kb + ((size_t)((b * NKV + h) * TT + t)) * HD + d) = o;
    } else {                                 // V, transposed store (d-major)
        int fv = f - NH * HD - NKV * HD;
        int h = fv / HD, d = fv % HD;
        Vt[((size_t)(b * NKV + h) * HD + d) * TT + t]     = u0;
        Vt[((size_t)(b * NKV + h) * HD + d + 1) * TT + t] = u1;
    }
}

// ---------------- causal GQA flash attention, swapped-QK^T 32x32 ----------------
// grid (16, NH, B): block = 128 q rows, 4 waves x 32 q. KVBLK=64, double-buffered
// LDS K/V (pre-swizzled source, linear GLDS dest). S^T = mfma(K,Q): lane owns one
// q-row -> softmax fully lane-local (defer-max). P->B-frag via cvt_pk + permlane32_swap.
__global__ __launch_bounds__(256) void k_attn(const u16* __restrict__ Q,
                                              const u16* __restrict__ Kb,
                                              const u16* __restrict__ Vt,
                                              u16* __restrict__ Y) {
    __shared__ u16 Ks[2][4096];      // [kv 64][d 64] swizzled (8KB per buf)
    __shared__ u16 Vs[2][4096];      // [d 64][kv 64] swizzled

    const int tid = threadIdx.x;
    const int w = tid >> 6, lane = tid & 63;
    const int ql = lane & 31, hi = lane >> 5;
    const int hi16 = hi << 4;
    const int b = blockIdx.z, h = blockIdx.y, kvh = h >> 2;

    const u16* qbase = Q  + ((size_t)(b * NH  + h  ) * TT) * HD;
    const u16* kbase = Kb + ((size_t)(b * NKV + kvh) * TT) * HD;
    const u16* vbase = Vt + ((size_t)(b * NKV + kvh) * HD) * TT;

    const int j    = 15 - (int)blockIdx.x;   // heavy blocks first
    const int qb   = j * 128;
    const int q0w  = qb + w * 32;
    const int nt   = 2 * j + 2;
    const int tmxw = (q0w + 31) >> 6;        // wave's diagonal tile index
    const int qabs = q0w + ql;               // this lane's q row

    // Q B-frags (d-slices of 16)
    s16x8 qf[4];
    #pragma unroll
    for (int ds = 0; ds < 4; ++ds)
        qf[ds] = *reinterpret_cast<const s16x8*>(qbase + (size_t)qabs * HD + ds * 16 + 8 * hi);
    asm volatile("s_waitcnt vmcnt(0)" ::: "memory");   // only stage loads counted after this

    // staging thread-constants: linear dest byte o -> (row, pre-swizzled col)
    const int o0 = w * 2048 + lane * 16, o1 = o0 + 1024;
    const int r0 = o0 >> 7, r1 = o1 >> 7;
    const int c0 = (o0 & 127) ^ ((r0 & 7) << 4);
    const int c1 = (o1 & 127) ^ ((r1 & 7) << 4);
    const size_t kof0 = (size_t)r0 * HD + (c0 >> 1);
    const size_t kof1 = (size_t)r1 * HD + (c1 >> 1);
    const size_t vof0 = (size_t)r0 * TT + (c0 >> 1);
    const size_t vof1 = (size_t)r1 * TT + (c1 >> 1);

    GLDS16(kbase + kof0, &Ks[0][w * 1024]);
    GLDS16(kbase + kof1, &Ks[0][w * 1024 + 512]);
    GLDS16(vbase + vof0, &Vs[0][w * 1024]);
    GLDS16(vbase + vof1, &Vs[0][w * 1024 + 512]);

    // per-lane read-address constants
    const char* KsB = (const char*)&Ks[0][0];
    const char* VsB = (const char*)&Vs[0][0];
    const int krb0 = (0 * 32 + ql) * 128, ksz0 = ((0 * 32 + ql) & 7) << 4;
    const int krb1 = (1 * 32 + ql) * 128, ksz1 = ((1 * 32 + ql) & 7) << 4;
    const int vrb0 = (0 * 32 + ql) * 128, vsz0 = ((0 * 32 + ql) & 7) << 4;
    const int vrb1 = (1 * 32 + ql) * 128, vsz1 = ((1 * 32 + ql) & 7) << 4;

    float mrow = -1e30f, lrowp = 0.f;
    f32x16 oT0 = {}, oT1 = {};               // O^T accumulators, d-tiles 0/1

    for (int t = 0; t < nt; ++t) {
        const int cur = t & 1;
        const int kv0 = t * 64;
        if (t + 1 < nt) {
            const size_t kb2 = (size_t)(kv0 + 64) * HD;
            GLDS16(kbase + kb2 + kof0, &Ks[cur ^ 1][w * 1024]);
            GLDS16(kbase + kb2 + kof1, &Ks[cur ^ 1][w * 1024 + 512]);
            GLDS16(vbase + (kv0 + 64) + vof0, &Vs[cur ^ 1][w * 1024]);
            GLDS16(vbase + (kv0 + 64) + vof1, &Vs[cur ^ 1][w * 1024 + 512]);
            asm volatile("s_waitcnt vmcnt(4)" ::: "memory");   // tile t resident, t+1 in flight
        } else {
            asm volatile("s_waitcnt vmcnt(0)" ::: "memory");
        }
        __builtin_amdgcn_s_barrier();
        __builtin_amdgcn_sched_barrier(0);

        if (t <= tmxw) {                     // wave-uniform causal skip
            const int bufo = cur * 8192;

            // S^T = K . Q^T  (two 32-kv sub-tiles)
            f32x16 sc0 = {}, sc1 = {};
            #pragma unroll
            for (int ds = 0; ds < 4; ++ds) {
                s16x8 k0 = *reinterpret_cast<const s16x8*>(KsB + bufo + krb0 + (((ds << 5) | hi16) ^ ksz0));
                s16x8 k1 = *reinterpret_cast<const s16x8*>(KsB + bufo + krb1 + (((ds << 5) | hi16) ^ ksz1));
                sc0 = __builtin_amdgcn_mfma_f32_32x32x16_bf16(k0, qf[ds], sc0, 0, 0, 0);
                sc1 = __builtin_amdgcn_mfma_f32_32x32x16_bf16(k1, qf[ds], sc1, 0, 0, 0);
            }

            float p0[16], p1[16];
            #pragma unroll
            for (int r = 0; r < 16; ++r) { p0[r] = sc0[r]; p1[r] = sc1[r]; }

            if (t == tmxw) {                 // mask only the diagonal tile
                const int dq = qabs - kv0 - 4 * hi;
                #pragma unroll
                for (int r = 0; r < 16; ++r) {
                    const int kr = (r & 3) + 8 * (r >> 2);
                    p0[r] = (kr      <= dq) ? p0[r] : -1e30f;
                    p1[r] = (kr + 32 <= dq) ? p1[r] : -1e30f;
                }
            }

            // defer-max: lane-local check, rare rescale
            float tmax = fmaxf(p0[0], p1[0]);
            #pragma unroll
            for (int r = 1; r < 16; ++r) tmax = fmaxf(tmax, fmaxf(p0[r], p1[r]));
            if (__any(tmax > mrow + 8.f)) {
                float tf = fmaxf(tmax, __shfl_xor(tmax, 32, 64));
                float mn = fmaxf(mrow, tf);
                float alpha = __builtin_amdgcn_exp2f(mrow - mn);
                mrow = mn;
                lrowp *= alpha;
                #pragma unroll
                for (int r = 0; r < 16; ++r) { oT0[r] *= alpha; oT1[r] *= alpha; }
            }

            float sum = 0.f;
            #pragma unroll
            for (int r = 0; r < 16; ++r) {
                p0[r] = __builtin_amdgcn_exp2f(p0[r] - mrow);
                p1[r] = __builtin_amdgcn_exp2f(p1[r] - mrow);
                sum += p0[r] + p1[r];
            }
            lrowp += sum;

            // PV: kt=0 sub-tile (P from p0)
            #pragma unroll
            for (int ks = 0; ks < 2; ++ks) {
                uint32_t a0 = cvtpk(p0[ks * 8 + 0], p0[ks * 8 + 1]);
                uint32_t b0 = cvtpk(p0[ks * 8 + 4], p0[ks * 8 + 5]);
                plswap(a0, b0);
                uint32_t a1 = cvtpk(p0[ks * 8 + 2], p0[ks * 8 + 3]);
                uint32_t b1 = cvtpk(p0[ks * 8 + 6], p0[ks * 8 + 7]);
                plswap(a1, b1);
                union { uint32_t d[4]; s16x8 v; } pb;
                pb.d[0] = a0; pb.d[1] = a1; pb.d[2] = b0; pb.d[3] = b1;
                const int colb = (0 << 6) | (ks << 5) | hi16;
                s16x8 v0 = *reinterpret_cast<const s16x8*>(VsB + bufo + vrb0 + (colb ^ vsz0));
                s16x8 v1 = *reinterpret_cast<const s16x8*>(VsB + bufo + vrb1 + (colb ^ vsz1));
                oT0 = __builtin_amdgcn_mfma_f32_32x32x16_bf16(v0, pb.v, oT0, 0, 0, 0);
                oT1 = __builtin_amdgcn_mfma_f32_32x32x16_bf16(v1, pb.v, oT1, 0, 0, 0);
            }
            // PV: kt=1 sub-tile (P from p1)
            #pragma unroll
            for (int ks = 0; ks < 2; ++ks) {
                uint32_t a0 = cvtpk(p1[ks * 8 + 0], p1[ks * 8 + 1]);
                uint32_t b0 = cvtpk(p1[ks * 8 + 4], p1[ks * 8 + 5]);
                plswap(a0, b0);
                uint32_t a1 = cvtpk(p1[ks * 8 + 2], p1[ks * 8 + 3]);
                uint32_t b1 = cvtpk(p1[ks * 8 + 6], p1[ks * 8 + 7]);
                plswap(a1, b1);
                union { uint32_t d[4]; s16x8 v; } pb;
                pb.d[0] = a0; pb.d[1] = a1; pb.d[2] = b0; pb.d[3] = b1;
                const int colb = (1 << 6) | (ks << 5) | hi16;
                s16x8 v0 = *reinterpret_cast<const s16x8*>(VsB + bufo + vrb0 + (colb ^ vsz0));
                s16x8 v1 = *reinterpret_cast<const s16x8*>(VsB + bufo + vrb1 + (colb ^ vsz1));
                oT0 = __builtin_amdgcn_mfma_f32_32x32x16_bf16(v0, pb.v, oT0, 0, 0, 0);
                oT1 = __builtin_amdgcn_mfma_f32_32x32x16_bf16(v1, pb.v, oT1, 0, 0, 0);
            }
        }

        __builtin_amdgcn_sched_barrier(0);
        __builtin_amdgcn_s_barrier();
    }

    // epilogue: combine lane-pair partial sums, normalize, write O^T -> Y rows
    lrowp += __shfl_xor(lrowp, 32, 64);
    const float rinv = 1.f / lrowp;
    const size_t yrow = ((size_t)(b * TT + qabs) * NH + h) * HD;
    #pragma unroll
    for (int rp = 0; rp < 8; ++rp) {
        const int d = ((2 * rp) & 3) + 8 * (rp >> 1) + 4 * hi;
        *reinterpret_cast<uint32_t*>(Y + yrow + d) =
            cvtpk(oT0[2 * rp] * rinv, oT0[2 * rp + 1] * rinv);
        *reinterpret_cast<uint32_t*>(Y + yrow + 32 + d) =
            cvtpk(oT1[2 * rp] * rinv, oT1[2 * rp + 1] * rinv);
    }
}

// ---------------- launch ----------------
extern "C" void kernel_launch(void* const* d_in, const int* in_sizes, int n_in,
                              void* d_out, int out_size, void* d_ws, size_t ws_size,
                              hipStream_t stream) {
    (void)in_sizes; (void)n_in; (void)out_size; (void)ws_size;
    const float* x     = (const float*)d_in[0];
    const float* wqkv  = (const float*)d_in[1];
    const float* wproj = (const float*)d_in[2];
    const float* fcos  = (const float*)d_in[3];
    const float* fsin  = (const float*)d_in[4];

    char* ws = (char*)d_ws;
    size_t off = 0;
    auto alloc = [&](size_t bytes) { void* p = ws + off; off += (bytes + 255) & ~(size_t)255; return p; };
    u16* Xbf  = (u16*)alloc((size_t)MM * CE * 2);
    u16* Wqb  = (u16*)alloc((size_t)QKVD * CE * 2);
    u16* Wpb  = (u16*)alloc((size_t)CE * CE * 2);
    u16* QKVb = (u16*)alloc((size_t)MM * QKVD * 2);
    u16* Qb   = (u16*)alloc((size_t)BB * NH * TT * HD * 2);
    u16* Kbuf = (u16*)alloc((size_t)BB * NKV * TT * HD * 2);
    u16* Vtb  = (u16*)alloc((size_t)BB * NKV * HD * TT * 2);
    u16* Yb   = (u16*)alloc((size_t)MM * CE * 2);

    k_f32_to_bf16<<<(MM * CE / 8 + 255) / 256, 256, 0, stream>>>(x, (uint32_t*)Xbf, MM * CE / 8);
    k_f32_to_bf16<<<(QKVD * CE / 8 + 255) / 256, 256, 0, stream>>>(wqkv, (uint32_t*)Wqb, QKVD * CE / 8);
    k_f32_to_bf16<<<(CE * CE / 8 + 255) / 256, 256, 0, stream>>>(wproj, (uint32_t*)Wpb, CE * CE / 8);

    dim3 g1(QKVD / 128, MM / 128);
    k_gemm_bt<true><<<g1, 256, 0, stream>>>(Xbf, Wqb, QKVb, MM, QKVD, CE);

    int pairs = MM * (QKVD / 2);
    k_rope_scatter<<<(pairs + 255) / 256, 256, 0, stream>>>(QKVb, fcos, fsin, Qb, Kbuf, Vtb);

    dim3 ga(16, NH, BB);
    k_attn<<<ga, 256, 0, stream>>>(Qb, Kbuf, Vtb, Yb);

    dim3 g2(CE / 128, MM / 128);
    k_gemm_bt<false><<<g2, 256, 0, stream>>>(Yb, Wpb, d_out, MM, CE, CE);
}

// Round 5
// 238.772 us; speedup vs baseline: 2.5805x; 1.1998x over previous
//
#include <hip/hip_runtime.h>
#include <hip/hip_bf16.h>
#include <cstdint>

#define NH   32
#define NKV  8
#define HD   64
#define CE   2048      // n_embd
#define BB   2
#define TT   2048
#define QKVD 3072      // (32 + 2*8) * 64
#define MM   (BB*TT)   // 4096 rows

typedef float  f32x4  __attribute__((ext_vector_type(4)));
typedef float  f32x16 __attribute__((ext_vector_type(16)));
typedef short  s16x8  __attribute__((ext_vector_type(8)));
typedef unsigned short u16;

#define AS1 __attribute__((address_space(1)))
#define AS3 __attribute__((address_space(3)))
#define GLDS16(src, dst) __builtin_amdgcn_global_load_lds( \
    (const AS1 uint32_t*)(src), (AS3 uint32_t*)(dst), 16, 0, 0)

static __device__ __forceinline__ float bf2f(u16 u) {
    union { uint32_t u; float f; } v; v.u = ((uint32_t)u) << 16; return v.f;
}
static __device__ __forceinline__ u16 f2bf(float f) {
    union { float f; uint32_t u; } v; v.f = f;
    uint32_t r = v.u + 0x7fffu + ((v.u >> 16) & 1u);   // RNE
    return (u16)(r >> 16);
}
static __device__ __forceinline__ uint32_t cvtpk(float lo, float hi) {
    uint32_t r;
    asm("v_cvt_pk_bf16_f32 %0, %1, %2" : "=v"(r) : "v"(lo), "v"(hi));
    return r;
}
// v_permlane32_swap_b32: a.hi32lanes <-> b.lo32lanes (both modified)
static __device__ __forceinline__ void plswap(uint32_t &a, uint32_t &b) {
    asm volatile("v_permlane32_swap_b32 %0, %1" : "+v"(a), "+v"(b));
}

// ---------------- fp32 -> bf16 convert (vectorized 8/thread, cvt_pk) ----------------
__global__ void k_f32_to_bf16(const float* __restrict__ in, uint32_t* __restrict__ out, int n8) {
    int i = blockIdx.x * blockDim.x + threadIdx.x;
    if (i >= n8) return;
    const float4* p = reinterpret_cast<const float4*>(in) + (size_t)i * 2;
    float4 a = p[0], b = p[1];
    uint4 o;
    o.x = cvtpk(a.x, a.y); o.y = cvtpk(a.z, a.w);
    o.z = cvtpk(b.x, b.y); o.w = cvtpk(b.z, b.w);
    *reinterpret_cast<uint4*>(out + (size_t)i * 4) = o;
}

// ---------------- bf16 GEMM (m97 structure): C(M,N) = A(M,K) @ B(N,K)^T ----------------
template<bool OUT_BF16>
__global__ __launch_bounds__(256) void k_gemm_bt(const u16* __restrict__ A,
                                                 const u16* __restrict__ Bm,
                                                 void* __restrict__ Cout,
                                                 int M, int N, int K) {
    __shared__ u16 As[128 * 32];
    __shared__ u16 Bs[128 * 32];
    const int tid  = threadIdx.x;
    const int m0   = blockIdx.y * 128;
    const int n0   = blockIdx.x * 128;
    const int w    = tid >> 6;
    const int lane = tid & 63;
    const int lr   = lane & 15, lg = lane >> 4;
    const int wm   = (w >> 1) * 64, wn = (w & 1) * 64;

    const int o0 = w * 2048 + lane * 16, o1 = o0 + 1024;
    const int ar0 = o0 >> 6, ar1 = o1 >> 6;
    const int ac0 = (o0 & 63) >> 1, ac1 = (o1 & 63) >> 1;
    const size_t aof0 = (size_t)(m0 + ar0) * K + ac0;
    const size_t aof1 = (size_t)(m0 + ar1) * K + ac1;
    const size_t bof0 = (size_t)(n0 + ar0) * K + ac0;
    const size_t bof1 = (size_t)(n0 + ar1) * K + ac1;
    u16* dA0 = &As[w * 1024];       u16* dA1 = &As[w * 1024 + 512];
    u16* dB0 = &Bs[w * 1024];       u16* dB1 = &Bs[w * 1024 + 512];

    f32x4 acc[4][4] = {};

    for (int k0 = 0; k0 < K; k0 += 32) {
        GLDS16(A  + aof0 + k0, dA0);
        GLDS16(A  + aof1 + k0, dA1);
        GLDS16(Bm + bof0 + k0, dB0);
        GLDS16(Bm + bof1 + k0, dB1);
        __syncthreads();
        s16x8 af[4], bf[4];
        #pragma unroll
        for (int i = 0; i < 4; ++i)
            af[i] = *reinterpret_cast<const s16x8*>(&As[(wm + i * 16 + lr) * 32 + lg * 8]);
        #pragma unroll
        for (int j = 0; j < 4; ++j)
            bf[j] = *reinterpret_cast<const s16x8*>(&Bs[(wn + j * 16 + lr) * 32 + lg * 8]);
        #pragma unroll
        for (int i = 0; i < 4; ++i)
            #pragma unroll
            for (int j = 0; j < 4; ++j)
                acc[i][j] = __builtin_amdgcn_mfma_f32_16x16x32_bf16(af[i], bf[j], acc[i][j], 0, 0, 0);
        __syncthreads();
    }

    #pragma unroll
    for (int i = 0; i < 4; ++i)
        #pragma unroll
        for (int j = 0; j < 4; ++j)
            #pragma unroll
            for (int r = 0; r < 4; ++r) {
                int m = m0 + wm + i * 16 + lg * 4 + r;
                int n = n0 + wn + j * 16 + lr;
                if constexpr (OUT_BF16)
                    reinterpret_cast<u16*>(Cout)[(size_t)m * N + n] = f2bf(acc[i][j][r]);
                else
                    reinterpret_cast<float*>(Cout)[(size_t)m * N + n] = acc[i][j][r];
            }
}

// ---------------- RoPE + scatter. Q gets scale*log2e folded in. ----------------
__global__ void k_rope_scatter(const u16* __restrict__ qkv,
                               const float* __restrict__ fcos,
                               const float* __restrict__ fsin,
                               u16* __restrict__ Q,
                               u16* __restrict__ Kb,
                               u16* __restrict__ Vt) {
    int p = blockIdx.x * blockDim.x + threadIdx.x;       // pair index
    if (p >= MM * (QKVD / 2)) return;
    int row = p / (QKVD / 2);
    int f   = (p % (QKVD / 2)) * 2;
    int b = row / TT, t = row % TT;
    uint32_t pk = reinterpret_cast<const uint32_t*>(qkv)[(size_t)row * (QKVD / 2) + (f >> 1)];
    u16 u0 = (u16)(pk & 0xffff), u1 = (u16)(pk >> 16);
    const float QS = 0.18033688011112042f;   // (1/sqrt(64)) * log2(e)
    if (f < NH * HD) {                       // Q with RoPE + folded softmax scale
        int h = f / HD, d = f % HD;
        float c = fcos[t * 32 + (d >> 1)], s = fsin[t * 32 + (d >> 1)];
        float x0 = bf2f(u0), x1 = bf2f(u1);
        uint32_t o = cvtpk((x0 * c - x1 * s) * QS, (x0 * s + x1 * c) * QS);
        *reinterpret_cast<uint32_t*>(Q + ((size_t)((b * NH + h) * TT + t)) * HD + d) = o;
    } else if (f < NH * HD + NKV * HD) {     // K with RoPE
        int fk = f - NH * HD;
        int h = fk / HD, d = fk % HD;
        float c = fcos[t * 32 + (d >> 1)], s = fsin[t * 32 + (d >> 1)];
        float x0 = bf2f(u0), x1 = bf2f(u1);
        uint32_t o = cvtpk(x0 * c - x1 * s, x0 * s + x1 * c);
        *reinterpret_cast<uint32_t*>(Kb + ((size_t)((b * NKV + h) * TT + t)) * HD + d) = o;
    } else {                                 // V, transposed store (d-major)
        int fv = f - NH * HD - NKV * HD;
        int h = fv / HD, d = fv % HD;
        Vt[((size_t)(b * NKV + h) * HD + d) * TT + t]     = u0;
        Vt[((size_t)(b * NKV + h) * HD + d + 1) * TT + t] = u1;
    }
}

// ---------------- causal GQA flash attention, swapped-QK^T 32x32, paired tiles ----
// grid (8, NH, B) = 512 blocks. Block processes q-tile pair {15-bx, bx} SEQUENTIALLY:
// per-block work = (32-2bx) + (2bx+2) = 34 kv-tile units, exactly uniform -> immune
// to CU<->blockIdx aliasing (R4 killer: all 4 blocks on a CU shared the same j).
// Per tile: S^T = mfma32x32(K,Q) -> lane-local softmax (defer-max) -> in-register
// P via cvt_pk+permlane32_swap -> O^T += mfma32x32(V,P). KV double-buffered LDS,
// GLDS16 with pre-swizzled source, counted vmcnt(4).
__global__ __launch_bounds__(256) void k_attn(const u16* __restrict__ Q,
                                              const u16* __restrict__ Kb,
                                              const u16* __restrict__ Vt,
                                              u16* __restrict__ Y) {
    __shared__ u16 Ks[2][4096];      // [kv 64][d 64] swizzled (8KB per buf)
    __shared__ u16 Vs[2][4096];      // [d 64][kv 64] swizzled

    const int tid = threadIdx.x;
    const int w = tid >> 6, lane = tid & 63;
    const int ql = lane & 31, hi = lane >> 5;
    const int hi16 = hi << 4;
    const int b = blockIdx.z, h = blockIdx.y, kvh = h >> 2;

    const u16* qbase = Q  + ((size_t)(b * NH  + h  ) * TT) * HD;
    const u16* kbase = Kb + ((size_t)(b * NKV + kvh) * TT) * HD;
    const u16* vbase = Vt + ((size_t)(b * NKV + kvh) * HD) * TT;

    // staging thread-constants: linear dest byte o -> (row, pre-swizzled col)
    const int o0 = w * 2048 + lane * 16, o1 = o0 + 1024;
    const int r0 = o0 >> 7, r1 = o1 >> 7;
    const int c0 = (o0 & 127) ^ ((r0 & 7) << 4);
    const int c1 = (o1 & 127) ^ ((r1 & 7) << 4);
    const size_t kof0 = (size_t)r0 * HD + (c0 >> 1);
    const size_t kof1 = (size_t)r1 * HD + (c1 >> 1);
    const size_t vof0 = (size_t)r0 * TT + (c0 >> 1);
    const size_t vof1 = (size_t)r1 * TT + (c1 >> 1);

    // per-lane read-address constants
    const char* KsB = (const char*)&Ks[0][0];
    const char* VsB = (const char*)&Vs[0][0];
    const int krb0 = (0 * 32 + ql) * 128, ksz0 = ((0 * 32 + ql) & 7) << 4;
    const int krb1 = (1 * 32 + ql) * 128, ksz1 = ((1 * 32 + ql) & 7) << 4;

    #pragma unroll 1
    for (int pi = 0; pi < 2; ++pi) {
        const int j    = pi ? (int)blockIdx.x : (15 - (int)blockIdx.x);
        const int q0w  = j * 128 + w * 32;
        const int nt   = 2 * j + 2;
        const int tmxw = (q0w + 31) >> 6;    // wave's diagonal tile index
        const int qabs = q0w + ql;           // this lane's q row

        // Q B-frags (d-slices of 16)
        s16x8 qf[4];
        #pragma unroll
        for (int ds = 0; ds < 4; ++ds)
            qf[ds] = *reinterpret_cast<const s16x8*>(qbase + (size_t)qabs * HD + ds * 16 + 8 * hi);
        asm volatile("s_waitcnt vmcnt(0)" ::: "memory");   // only stage loads counted after this

        GLDS16(kbase + kof0, &Ks[0][w * 1024]);
        GLDS16(kbase + kof1, &Ks[0][w * 1024 + 512]);
        GLDS16(vbase + vof0, &Vs[0][w * 1024]);
        GLDS16(vbase + vof1, &Vs[0][w * 1024 + 512]);

        float mrow = -1e30f, lrowp = 0.f;
        f32x16 oT0 = {}, oT1 = {};           // O^T accumulators, d-tiles 0/1

        for (int t = 0; t < nt; ++t) {
            const int cur = t & 1;
            const int kv0 = t * 64;
            if (t + 1 < nt) {
                const size_t kb2 = (size_t)(kv0 + 64) * HD;
                GLDS16(kbase + kb2 + kof0, &Ks[cur ^ 1][w * 1024]);
                GLDS16(kbase + kb2 + kof1, &Ks[cur ^ 1][w * 1024 + 512]);
                GLDS16(vbase + (kv0 + 64) + vof0, &Vs[cur ^ 1][w * 1024]);
                GLDS16(vbase + (kv0 + 64) + vof1, &Vs[cur ^ 1][w * 1024 + 512]);
                asm volatile("s_waitcnt vmcnt(4)" ::: "memory");   // tile t resident, t+1 in flight
            } else {
                asm volatile("s_waitcnt vmcnt(0)" ::: "memory");
            }
            __builtin_amdgcn_s_barrier();
            __builtin_amdgcn_sched_barrier(0);

            if (t <= tmxw) {                 // wave-uniform causal skip
                const int bufo = cur * 8192;

                // S^T = K . Q^T  (two 32-kv sub-tiles)
                f32x16 sc0 = {}, sc1 = {};
                #pragma unroll
                for (int ds = 0; ds < 4; ++ds) {
                    s16x8 k0 = *reinterpret_cast<const s16x8*>(KsB + bufo + krb0 + (((ds << 5) | hi16) ^ ksz0));
                    s16x8 k1 = *reinterpret_cast<const s16x8*>(KsB + bufo + krb1 + (((ds << 5) | hi16) ^ ksz1));
                    sc0 = __builtin_amdgcn_mfma_f32_32x32x16_bf16(k0, qf[ds], sc0, 0, 0, 0);
                    sc1 = __builtin_amdgcn_mfma_f32_32x32x16_bf16(k1, qf[ds], sc1, 0, 0, 0);
                }

                float p0[16], p1[16];
                #pragma unroll
                for (int r = 0; r < 16; ++r) { p0[r] = sc0[r]; p1[r] = sc1[r]; }

                if (t == tmxw) {             // mask only the diagonal tile
                    const int dq = qabs - kv0 - 4 * hi;
                    #pragma unroll
                    for (int r = 0; r < 16; ++r) {
                        const int kr = (r & 3) + 8 * (r >> 2);
                        p0[r] = (kr      <= dq) ? p0[r] : -1e30f;
                        p1[r] = (kr + 32 <= dq) ? p1[r] : -1e30f;
                    }
                }

                // defer-max: lane-local check, rare rescale
                float tmax = fmaxf(p0[0], p1[0]);
                #pragma unroll
                for (int r = 1; r < 16; ++r) tmax = fmaxf(tmax, fmaxf(p0[r], p1[r]));
                if (__any(tmax > mrow + 8.f)) {
                    float tf = fmaxf(tmax, __shfl_xor(tmax, 32, 64));
                    float mn = fmaxf(mrow, tf);
                    float alpha = __builtin_amdgcn_exp2f(mrow - mn);
                    mrow = mn;
                    lrowp *= alpha;
                    #pragma unroll
                    for (int r = 0; r < 16; ++r) { oT0[r] *= alpha; oT1[r] *= alpha; }
                }

                float sum = 0.f;
                #pragma unroll
                for (int r = 0; r < 16; ++r) {
                    p0[r] = __builtin_amdgcn_exp2f(p0[r] - mrow);
                    p1[r] = __builtin_amdgcn_exp2f(p1[r] - mrow);
                    sum += p0[r] + p1[r];
                }
                lrowp += sum;

                // PV: kt=0 sub-tile (P from p0)
                #pragma unroll
                for (int ks = 0; ks < 2; ++ks) {
                    uint32_t a0 = cvtpk(p0[ks * 8 + 0], p0[ks * 8 + 1]);
                    uint32_t b0 = cvtpk(p0[ks * 8 + 4], p0[ks * 8 + 5]);
                    plswap(a0, b0);
                    uint32_t a1 = cvtpk(p0[ks * 8 + 2], p0[ks * 8 + 3]);
                    uint32_t b1 = cvtpk(p0[ks * 8 + 6], p0[ks * 8 + 7]);
                    plswap(a1, b1);
                    union { uint32_t d[4]; s16x8 v; } pb;
                    pb.d[0] = a0; pb.d[1] = a1; pb.d[2] = b0; pb.d[3] = b1;
                    const int colb = (0 << 6) | (ks << 5) | hi16;
                    s16x8 v0 = *reinterpret_cast<const s16x8*>(VsB + bufo + krb0 + (colb ^ ksz0));
                    s16x8 v1 = *reinterpret_cast<const s16x8*>(VsB + bufo + krb1 + (colb ^ ksz1));
                    oT0 = __builtin_amdgcn_mfma_f32_32x32x16_bf16(v0, pb.v, oT0, 0, 0, 0);
                    oT1 = __builtin_amdgcn_mfma_f32_32x32x16_bf16(v1, pb.v, oT1, 0, 0, 0);
                }
                // PV: kt=1 sub-tile (P from p1)
                #pragma unroll
                for (int ks = 0; ks < 2; ++ks) {
                    uint32_t a0 = cvtpk(p1[ks * 8 + 0], p1[ks * 8 + 1]);
                    uint32_t b0 = cvtpk(p1[ks * 8 + 4], p1[ks * 8 + 5]);
                    plswap(a0, b0);
                    uint32_t a1 = cvtpk(p1[ks * 8 + 2], p1[ks * 8 + 3]);
                    uint32_t b1 = cvtpk(p1[ks * 8 + 6], p1[ks * 8 + 7]);
                    plswap(a1, b1);
                    union { uint32_t d[4]; s16x8 v; } pb;
                    pb.d[0] = a0; pb.d[1] = a1; pb.d[2] = b0; pb.d[3] = b1;
                    const int colb = (1 << 6) | (ks << 5) | hi16;
                    s16x8 v0 = *reinterpret_cast<const s16x8*>(VsB + bufo + krb0 + (colb ^ ksz0));
                    s16x8 v1 = *reinterpret_cast<const s16x8*>(VsB + bufo + krb1 + (colb ^ ksz1));
                    oT0 = __builtin_amdgcn_mfma_f32_32x32x16_bf16(v0, pb.v, oT0, 0, 0, 0);
                    oT1 = __builtin_amdgcn_mfma_f32_32x32x16_bf16(v1, pb.v, oT1, 0, 0, 0);
                }
            }

            __builtin_amdgcn_sched_barrier(0);
            __builtin_amdgcn_s_barrier();
        }

        // epilogue: combine lane-pair partial sums, normalize, write O^T -> Y rows
        lrowp += __shfl_xor(lrowp, 32, 64);
        const float rinv = 1.f / lrowp;
        const size_t yrow = ((size_t)(b * TT + qabs) * NH + h) * HD;
        #pragma unroll
        for (int rp = 0; rp < 8; ++rp) {
            const int d = ((2 * rp) & 3) + 8 * (rp >> 1) + 4 * hi;
            *reinterpret_cast<uint32_t*>(Y + yrow + d) =
                cvtpk(oT0[2 * rp] * rinv, oT0[2 * rp + 1] * rinv);
            *reinterpret_cast<uint32_t*>(Y + yrow + 32 + d) =
                cvtpk(oT1[2 * rp] * rinv, oT1[2 * rp + 1] * rinv);
        }
    }
}

// ---------------- launch ----------------
extern "C" void kernel_launch(void* const* d_in, const int* in_sizes, int n_in,
                              void* d_out, int out_size, void* d_ws, size_t ws_size,
                              hipStream_t stream) {
    (void)in_sizes; (void)n_in; (void)out_size; (void)ws_size;
    const float* x     = (const float*)d_in[0];
    const float* wqkv  = (const float*)d_in[1];
    const float* wproj = (const float*)d_in[2];
    const float* fcos  = (const float*)d_in[3];
    const float* fsin  = (const float*)d_in[4];

    char* ws = (char*)d_ws;
    size_t off = 0;
    auto alloc = [&](size_t bytes) { void* p = ws + off; off += (bytes + 255) & ~(size_t)255; return p; };
    u16* Xbf  = (u16*)alloc((size_t)MM * CE * 2);
    u16* Wqb  = (u16*)alloc((size_t)QKVD * CE * 2);
    u16* Wpb  = (u16*)alloc((size_t)CE * CE * 2);
    u16* QKVb = (u16*)alloc((size_t)MM * QKVD * 2);
    u16* Qb   = (u16*)alloc((size_t)BB * NH * TT * HD * 2);
    u16* Kbuf = (u16*)alloc((size_t)BB * NKV * TT * HD * 2);
    u16* Vtb  = (u16*)alloc((size_t)BB * NKV * HD * TT * 2);
    u16* Yb   = (u16*)alloc((size_t)MM * CE * 2);

    k_f32_to_bf16<<<(MM * CE / 8 + 255) / 256, 256, 0, stream>>>(x, (uint32_t*)Xbf, MM * CE / 8);
    k_f32_to_bf16<<<(QKVD * CE / 8 + 255) / 256, 256, 0, stream>>>(wqkv, (uint32_t*)Wqb, QKVD * CE / 8);
    k_f32_to_bf16<<<(CE * CE / 8 + 255) / 256, 256, 0, stream>>>(wproj, (uint32_t*)Wpb, CE * CE / 8);

    dim3 g1(QKVD / 128, MM / 128);
    k_gemm_bt<true><<<g1, 256, 0, stream>>>(Xbf, Wqb, QKVb, MM, QKVD, CE);

    int pairs = MM * (QKVD / 2);
    k_rope_scatter<<<(pairs + 255) / 256, 256, 0, stream>>>(QKVb, fcos, fsin, Qb, Kbuf, Vtb);

    dim3 ga(8, NH, BB);
    k_attn<<<ga, 256, 0, stream>>>(Qb, Kbuf, Vtb, Yb);

    dim3 g2(CE / 128, MM / 128);
    k_gemm_bt<false><<<g2, 256, 0, stream>>>(Yb, Wpb, d_out, MM, CE, CE);
}

// Round 6
// 215.356 us; speedup vs baseline: 2.8611x; 1.1087x over previous
//
#include <hip/hip_runtime.h>
#include <hip/hip_bf16.h>
#include <cstdint>

#define NH   32
#define NKV  8
#define HD   64
#define CE   2048      // n_embd
#define BB   2
#define TT   2048
#define QKVD 3072      // (32 + 2*8) * 64
#define MM   (BB*TT)   // 4096 rows

typedef float  f32x4  __attribute__((ext_vector_type(4)));
typedef float  f32x16 __attribute__((ext_vector_type(16)));
typedef short  s16x8  __attribute__((ext_vector_type(8)));
typedef unsigned short u16;

#define AS1 __attribute__((address_space(1)))
#define AS3 __attribute__((address_space(3)))
#define GLDS16(src, dst) __builtin_amdgcn_global_load_lds( \
    (const AS1 uint32_t*)(src), (AS3 uint32_t*)(dst), 16, 0, 0)

static __device__ __forceinline__ float bf2f(u16 u) {
    union { uint32_t u; float f; } v; v.u = ((uint32_t)u) << 16; return v.f;
}
static __device__ __forceinline__ u16 f2bf(float f) {
    union { float f; uint32_t u; } v; v.f = f;
    uint32_t r = v.u + 0x7fffu + ((v.u >> 16) & 1u);   // RNE
    return (u16)(r >> 16);
}
static __device__ __forceinline__ uint32_t cvtpk(float lo, float hi) {
    uint32_t r;
    asm("v_cvt_pk_bf16_f32 %0, %1, %2" : "=v"(r) : "v"(lo), "v"(hi));
    return r;
}
// v_permlane32_swap_b32: a.hi32lanes <-> b.lo32lanes (both modified)
static __device__ __forceinline__ void plswap(uint32_t &a, uint32_t &b) {
    asm volatile("v_permlane32_swap_b32 %0, %1" : "+v"(a), "+v"(b));
}

// ---------------- fp32 -> bf16 convert (vectorized 8/thread, cvt_pk) ----------------
__global__ void k_f32_to_bf16(const float* __restrict__ in, uint32_t* __restrict__ out, int n8) {
    int i = blockIdx.x * blockDim.x + threadIdx.x;
    if (i >= n8) return;
    const float4* p = reinterpret_cast<const float4*>(in) + (size_t)i * 2;
    float4 a = p[0], b = p[1];
    uint4 o;
    o.x = cvtpk(a.x, a.y); o.y = cvtpk(a.z, a.w);
    o.z = cvtpk(b.x, b.y); o.w = cvtpk(b.z, b.w);
    *reinterpret_cast<uint4*>(out + (size_t)i * 4) = o;
}

// ============ QKV GEMM with fused RoPE + scatter epilogue ============
// C(M=4096, N=3072) = Xbf @ Wqb^T; epilogue applies RoPE to Q/K cols (pairs live
// in adjacent lanes -> shfl_xor(1)) and scatters to Q(B,H,T,D), K(B,KVH,T,D),
// Vt(B,KVH,D,T). Grid (24,32) remapped via bijective XCD-chunk swizzle.
__global__ __launch_bounds__(256) void k_gemm_qkv(const u16* __restrict__ A,
                                                  const u16* __restrict__ Bm,
                                                  u16* __restrict__ Qb,
                                                  u16* __restrict__ Kb,
                                                  u16* __restrict__ Vt,
                                                  const float* __restrict__ fcos,
                                                  const float* __restrict__ fsin) {
    __shared__ u16 As[128 * 32];
    __shared__ u16 Bs[128 * 32];
    const int K = CE;
    // XCD swizzle: 768 wgs, q=96 per XCD chunk
    const int c  = blockIdx.x + 24 * blockIdx.y;
    const int nc = (c & 7) * 96 + (c >> 3);
    const int m0 = (nc / 24) * 128;
    const int n0 = (nc % 24) * 128;

    const int tid  = threadIdx.x;
    const int w    = tid >> 6;
    const int lane = tid & 63;
    const int lr   = lane & 15, lg = lane >> 4;
    const int wm   = (w >> 1) * 64, wn = (w & 1) * 64;

    const int o0 = w * 2048 + lane * 16, o1 = o0 + 1024;
    const int ar0 = o0 >> 6, ar1 = o1 >> 6;
    const int ac0 = (o0 & 63) >> 1, ac1 = (o1 & 63) >> 1;
    const size_t aof0 = (size_t)(m0 + ar0) * K + ac0;
    const size_t aof1 = (size_t)(m0 + ar1) * K + ac1;
    const size_t bof0 = (size_t)(n0 + ar0) * K + ac0;
    const size_t bof1 = (size_t)(n0 + ar1) * K + ac1;
    u16* dA0 = &As[w * 1024];       u16* dA1 = &As[w * 1024 + 512];
    u16* dB0 = &Bs[w * 1024];       u16* dB1 = &Bs[w * 1024 + 512];

    f32x4 acc[4][4] = {};

    for (int k0 = 0; k0 < K; k0 += 32) {
        GLDS16(A  + aof0 + k0, dA0);
        GLDS16(A  + aof1 + k0, dA1);
        GLDS16(Bm + bof0 + k0, dB0);
        GLDS16(Bm + bof1 + k0, dB1);
        __syncthreads();
        s16x8 af[4], bf[4];
        #pragma unroll
        for (int i = 0; i < 4; ++i)
            af[i] = *reinterpret_cast<const s16x8*>(&As[(wm + i * 16 + lr) * 32 + lg * 8]);
        #pragma unroll
        for (int j = 0; j < 4; ++j)
            bf[j] = *reinterpret_cast<const s16x8*>(&Bs[(wn + j * 16 + lr) * 32 + lg * 8]);
        #pragma unroll
        for (int i = 0; i < 4; ++i)
            #pragma unroll
            for (int j = 0; j < 4; ++j)
                acc[i][j] = __builtin_amdgcn_mfma_f32_16x16x32_bf16(af[i], bf[j], acc[i][j], 0, 0, 0);
        __syncthreads();
    }

    // fused epilogue
    const float QS = 0.18033688011112042f;   // (1/sqrt(64)) * log2(e)
    const int bb = m0 / TT;
    const int tb = m0 - bb * TT + wm;
    #pragma unroll
    for (int i = 0; i < 4; ++i) {
        const int t0 = tb + i * 16 + lg * 4;
        #pragma unroll
        for (int j = 0; j < 4; ++j) {
            const int n = n0 + wn + j * 16 + lr;
            if (n0 < NH * HD) {                      // ---- Q: RoPE + QS ----
                const int hh = n >> 6, d = n & 63;
                #pragma unroll
                for (int r = 0; r < 4; ++r) {
                    const int t = t0 + r;
                    const float cc = fcos[t * 32 + (d >> 1)];
                    const float ss = fsin[t * 32 + (d >> 1)];
                    float v = acc[i][j][r];
                    float p = __shfl_xor(v, 1, 64);
                    float o = ((lr & 1) ? (p * ss + v * cc) : (v * cc - p * ss)) * QS;
                    float po = __shfl_xor(o, 1, 64);
                    if (!(lr & 1))
                        *reinterpret_cast<uint32_t*>(Qb + ((size_t)((bb * NH + hh) * TT + t)) * HD + d) = cvtpk(o, po);
                }
            } else if (n0 < (NH + NKV) * HD) {       // ---- K: RoPE ----
                const int fk = n - NH * HD;
                const int hh = fk >> 6, d = fk & 63;
                #pragma unroll
                for (int r = 0; r < 4; ++r) {
                    const int t = t0 + r;
                    const float cc = fcos[t * 32 + (d >> 1)];
                    const float ss = fsin[t * 32 + (d >> 1)];
                    float v = acc[i][j][r];
                    float p = __shfl_xor(v, 1, 64);
                    float o = (lr & 1) ? (p * ss + v * cc) : (v * cc - p * ss);
                    float po = __shfl_xor(o, 1, 64);
                    if (!(lr & 1))
                        *reinterpret_cast<uint32_t*>(Kb + ((size_t)((bb * NKV + hh) * TT + t)) * HD + d) = cvtpk(o, po);
                }
            } else {                                  // ---- V: transpose store ----
                const int fv = n - (NH + NKV) * HD;
                const int vh = fv >> 6, d = fv & 63;
                uint2 st;
                st.x = cvtpk(acc[i][j][0], acc[i][j][1]);
                st.y = cvtpk(acc[i][j][2], acc[i][j][3]);
                *reinterpret_cast<uint2*>(Vt + ((size_t)(bb * NKV + vh) * HD + d) * TT + t0) = st;
            }
        }
    }
}

// ---------------- bf16 GEMM, f32 out (proj): C(M,N) = A(M,K) @ B(N,K)^T ----------------
__global__ __launch_bounds__(256) void k_gemm_bt(const u16* __restrict__ A,
                                                 const u16* __restrict__ Bm,
                                                 float* __restrict__ Cout,
                                                 int M, int N, int K) {
    __shared__ u16 As[128 * 32];
    __shared__ u16 Bs[128 * 32];
    // XCD swizzle: 512 wgs, q=64 per XCD chunk
    const int c  = blockIdx.x + 16 * blockIdx.y;
    const int nc = (c & 7) * 64 + (c >> 3);
    const int m0 = (nc >> 4) * 128;
    const int n0 = (nc & 15) * 128;

    const int tid  = threadIdx.x;
    const int w    = tid >> 6;
    const int lane = tid & 63;
    const int lr   = lane & 15, lg = lane >> 4;
    const int wm   = (w >> 1) * 64, wn = (w & 1) * 64;

    const int o0 = w * 2048 + lane * 16, o1 = o0 + 1024;
    const int ar0 = o0 >> 6, ar1 = o1 >> 6;
    const int ac0 = (o0 & 63) >> 1, ac1 = (o1 & 63) >> 1;
    const size_t aof0 = (size_t)(m0 + ar0) * K + ac0;
    const size_t aof1 = (size_t)(m0 + ar1) * K + ac1;
    const size_t bof0 = (size_t)(n0 + ar0) * K + ac0;
    const size_t bof1 = (size_t)(n0 + ar1) * K + ac1;
    u16* dA0 = &As[w * 1024];       u16* dA1 = &As[w * 1024 + 512];
    u16* dB0 = &Bs[w * 1024];       u16* dB1 = &Bs[w * 1024 + 512];

    f32x4 acc[4][4] = {};

    for (int k0 = 0; k0 < K; k0 += 32) {
        GLDS16(A  + aof0 + k0, dA0);
        GLDS16(A  + aof1 + k0, dA1);
        GLDS16(Bm + bof0 + k0, dB0);
        GLDS16(Bm + bof1 + k0, dB1);
        __syncthreads();
        s16x8 af[4], bf[4];
        #pragma unroll
        for (int i = 0; i < 4; ++i)
            af[i] = *reinterpret_cast<const s16x8*>(&As[(wm + i * 16 + lr) * 32 + lg * 8]);
        #pragma unroll
        for (int j = 0; j < 4; ++j)
            bf[j] = *reinterpret_cast<const s16x8*>(&Bs[(wn + j * 16 + lr) * 32 + lg * 8]);
        #pragma unroll
        for (int i = 0; i < 4; ++i)
            #pragma unroll
            for (int j = 0; j < 4; ++j)
                acc[i][j] = __builtin_amdgcn_mfma_f32_16x16x32_bf16(af[i], bf[j], acc[i][j], 0, 0, 0);
        __syncthreads();
    }

    #pragma unroll
    for (int i = 0; i < 4; ++i)
        #pragma unroll
        for (int j = 0; j < 4; ++j)
            #pragma unroll
            for (int r = 0; r < 4; ++r) {
                int m = m0 + wm + i * 16 + lg * 4 + r;
                int n = n0 + wn + j * 16 + lr;
                Cout[(size_t)m * N + n] = acc[i][j][r];
            }
}

// ---------------- causal GQA flash attention, swapped-QK^T 32x32, paired tiles ----
// grid (8, NH, B) = 512 blocks; block does q-tile pair {15-bx, bx} sequentially
// (34 kv-tile units/block, exactly uniform). Per tile: S^T = mfma32x32(K,Q) ->
// lane-local softmax (defer-max) -> in-register P via cvt_pk+permlane32_swap ->
// O^T += mfma32x32(V,P). KV double-buffered LDS, GLDS16 pre-swizzled source,
// counted vmcnt(4); s_setprio(1) around MFMA clusters.
__global__ __launch_bounds__(256) void k_attn(const u16* __restrict__ Q,
                                              const u16* __restrict__ Kb,
                                              const u16* __restrict__ Vt,
                                              u16* __restrict__ Y) {
    __shared__ u16 Ks[2][4096];      // [kv 64][d 64] swizzled (8KB per buf)
    __shared__ u16 Vs[2][4096];      // [d 64][kv 64] swizzled

    const int tid = threadIdx.x;
    const int w = tid >> 6, lane = tid & 63;
    const int ql = lane & 31, hi = lane >> 5;
    const int hi16 = hi << 4;
    const int b = blockIdx.z, h = blockIdx.y, kvh = h >> 2;

    const u16* qbase = Q  + ((size_t)(b * NH  + h  ) * TT) * HD;
    const u16* kbase = Kb + ((size_t)(b * NKV + kvh) * TT) * HD;
    const u16* vbase = Vt + ((size_t)(b * NKV + kvh) * HD) * TT;

    // staging thread-constants: linear dest byte o -> (row, pre-swizzled col)
    const int o0 = w * 2048 + lane * 16, o1 = o0 + 1024;
    const int r0 = o0 >> 7, r1 = o1 >> 7;
    const int c0 = (o0 & 127) ^ ((r0 & 7) << 4);
    const int c1 = (o1 & 127) ^ ((r1 & 7) << 4);
    const size_t kof0 = (size_t)r0 * HD + (c0 >> 1);
    const size_t kof1 = (size_t)r1 * HD + (c1 >> 1);
    const size_t vof0 = (size_t)r0 * TT + (c0 >> 1);
    const size_t vof1 = (size_t)r1 * TT + (c1 >> 1);

    // per-lane read-address constants
    const char* KsB = (const char*)&Ks[0][0];
    const char* VsB = (const char*)&Vs[0][0];
    const int krb0 = (0 * 32 + ql) * 128, ksz0 = ((0 * 32 + ql) & 7) << 4;
    const int krb1 = (1 * 32 + ql) * 128, ksz1 = ((1 * 32 + ql) & 7) << 4;

    #pragma unroll 1
    for (int pi = 0; pi < 2; ++pi) {
        const int j    = pi ? (int)blockIdx.x : (15 - (int)blockIdx.x);
        const int q0w  = j * 128 + w * 32;
        const int nt   = 2 * j + 2;
        const int tmxw = (q0w + 31) >> 6;    // wave's diagonal tile index
        const int qabs = q0w + ql;           // this lane's q row

        // Q B-frags (d-slices of 16)
        s16x8 qf[4];
        #pragma unroll
        for (int ds = 0; ds < 4; ++ds)
            qf[ds] = *reinterpret_cast<const s16x8*>(qbase + (size_t)qabs * HD + ds * 16 + 8 * hi);
        asm volatile("s_waitcnt vmcnt(0)" ::: "memory");   // only stage loads counted after this

        GLDS16(kbase + kof0, &Ks[0][w * 1024]);
        GLDS16(kbase + kof1, &Ks[0][w * 1024 + 512]);
        GLDS16(vbase + vof0, &Vs[0][w * 1024]);
        GLDS16(vbase + vof1, &Vs[0][w * 1024 + 512]);

        float mrow = -1e30f, lrowp = 0.f;
        f32x16 oT0 = {}, oT1 = {};           // O^T accumulators, d-tiles 0/1

        for (int t = 0; t < nt; ++t) {
            const int cur = t & 1;
            const int kv0 = t * 64;
            if (t + 1 < nt) {
                const size_t kb2 = (size_t)(kv0 + 64) * HD;
                GLDS16(kbase + kb2 + kof0, &Ks[cur ^ 1][w * 1024]);
                GLDS16(kbase + kb2 + kof1, &Ks[cur ^ 1][w * 1024 + 512]);
                GLDS16(vbase + (kv0 + 64) + vof0, &Vs[cur ^ 1][w * 1024]);
                GLDS16(vbase + (kv0 + 64) + vof1, &Vs[cur ^ 1][w * 1024 + 512]);
                asm volatile("s_waitcnt vmcnt(4)" ::: "memory");   // tile t resident, t+1 in flight
            } else {
                asm volatile("s_waitcnt vmcnt(0)" ::: "memory");
            }
            __builtin_amdgcn_s_barrier();
            __builtin_amdgcn_sched_barrier(0);

            if (t <= tmxw) {                 // wave-uniform causal skip
                const int bufo = cur * 8192;

                // S^T = K . Q^T  (two 32-kv sub-tiles)
                f32x16 sc0 = {}, sc1 = {};
                __builtin_amdgcn_s_setprio(1);
                #pragma unroll
                for (int ds = 0; ds < 4; ++ds) {
                    s16x8 k0 = *reinterpret_cast<const s16x8*>(KsB + bufo + krb0 + (((ds << 5) | hi16) ^ ksz0));
                    s16x8 k1 = *reinterpret_cast<const s16x8*>(KsB + bufo + krb1 + (((ds << 5) | hi16) ^ ksz1));
                    sc0 = __builtin_amdgcn_mfma_f32_32x32x16_bf16(k0, qf[ds], sc0, 0, 0, 0);
                    sc1 = __builtin_amdgcn_mfma_f32_32x32x16_bf16(k1, qf[ds], sc1, 0, 0, 0);
                }
                __builtin_amdgcn_s_setprio(0);

                float p0[16], p1[16];
                #pragma unroll
                for (int r = 0; r < 16; ++r) { p0[r] = sc0[r]; p1[r] = sc1[r]; }

                if (t == tmxw) {             // mask only the diagonal tile
                    const int dq = qabs - kv0 - 4 * hi;
                    #pragma unroll
                    for (int r = 0; r < 16; ++r) {
                        const int kr = (r & 3) + 8 * (r >> 2);
                        p0[r] = (kr      <= dq) ? p0[r] : -1e30f;
                        p1[r] = (kr + 32 <= dq) ? p1[r] : -1e30f;
                    }
                }

                // defer-max: lane-local check, rare rescale
                float tmax = fmaxf(p0[0], p1[0]);
                #pragma unroll
                for (int r = 1; r < 16; ++r) tmax = fmaxf(tmax, fmaxf(p0[r], p1[r]));
                if (__any(tmax > mrow + 8.f)) {
                    float tf = fmaxf(tmax, __shfl_xor(tmax, 32, 64));
                    float mn = fmaxf(mrow, tf);
                    float alpha = __builtin_amdgcn_exp2f(mrow - mn);
                    mrow = mn;
                    lrowp *= alpha;
                    #pragma unroll
                    for (int r = 0; r < 16; ++r) { oT0[r] *= alpha; oT1[r] *= alpha; }
                }

                float sum = 0.f;
                #pragma unroll
                for (int r = 0; r < 16; ++r) {
                    p0[r] = __builtin_amdgcn_exp2f(p0[r] - mrow);
                    p1[r] = __builtin_amdgcn_exp2f(p1[r] - mrow);
                    sum += p0[r] + p1[r];
                }
                lrowp += sum;

                __builtin_amdgcn_s_setprio(1);
                // PV: kt=0 sub-tile (P from p0)
                #pragma unroll
                for (int ks = 0; ks < 2; ++ks) {
                    uint32_t a0 = cvtpk(p0[ks * 8 + 0], p0[ks * 8 + 1]);
                    uint32_t b0 = cvtpk(p0[ks * 8 + 4], p0[ks * 8 + 5]);
                    plswap(a0, b0);
                    uint32_t a1 = cvtpk(p0[ks * 8 + 2], p0[ks * 8 + 3]);
                    uint32_t b1 = cvtpk(p0[ks * 8 + 6], p0[ks * 8 + 7]);
                    plswap(a1, b1);
                    union { uint32_t d[4]; s16x8 v; } pb;
                    pb.d[0] = a0; pb.d[1] = a1; pb.d[2] = b0; pb.d[3] = b1;
                    const int colb = (0 << 6) | (ks << 5) | hi16;
                    s16x8 v0 = *reinterpret_cast<const s16x8*>(VsB + bufo + krb0 + (colb ^ ksz0));
                    s16x8 v1 = *reinterpret_cast<const s16x8*>(VsB + bufo + krb1 + (colb ^ ksz1));
                    oT0 = __builtin_amdgcn_mfma_f32_32x32x16_bf16(v0, pb.v, oT0, 0, 0, 0);
                    oT1 = __builtin_amdgcn_mfma_f32_32x32x16_bf16(v1, pb.v, oT1, 0, 0, 0);
                }
                // PV: kt=1 sub-tile (P from p1)
                #pragma unroll
                for (int ks = 0; ks < 2; ++ks) {
                    uint32_t a0 = cvtpk(p1[ks * 8 + 0], p1[ks * 8 + 1]);
                    uint32_t b0 = cvtpk(p1[ks * 8 + 4], p1[ks * 8 + 5]);
                    plswap(a0, b0);
                    uint32_t a1 = cvtpk(p1[ks * 8 + 2], p1[ks * 8 + 3]);
                    uint32_t b1 = cvtpk(p1[ks * 8 + 6], p1[ks * 8 + 7]);
                    plswap(a1, b1);
                    union { uint32_t d[4]; s16x8 v; } pb;
                    pb.d[0] = a0; pb.d[1] = a1; pb.d[2] = b0; pb.d[3] = b1;
                    const int colb = (1 << 6) | (ks << 5) | hi16;
                    s16x8 v0 = *reinterpret_cast<const s16x8*>(VsB + bufo + krb0 + (colb ^ ksz0));
                    s16x8 v1 = *reinterpret_cast<const s16x8*>(VsB + bufo + krb1 + (colb ^ ksz1));
                    oT0 = __builtin_amdgcn_mfma_f32_32x32x16_bf16(v0, pb.v, oT0, 0, 0, 0);
                    oT1 = __builtin_amdgcn_mfma_f32_32x32x16_bf16(v1, pb.v, oT1, 0, 0, 0);
                }
                __builtin_amdgcn_s_setprio(0);
            }

            __builtin_amdgcn_sched_barrier(0);
            __builtin_amdgcn_s_barrier();
        }

        // epilogue: combine lane-pair partial sums, normalize, write O^T -> Y rows
        lrowp += __shfl_xor(lrowp, 32, 64);
        const float rinv = 1.f / lrowp;
        const size_t yrow = ((size_t)(b * TT + qabs) * NH + h) * HD;
        #pragma unroll
        for (int rp = 0; rp < 8; ++rp) {
            const int d = ((2 * rp) & 3) + 8 * (rp >> 1) + 4 * hi;
            *reinterpret_cast<uint32_t*>(Y + yrow + d) =
                cvtpk(oT0[2 * rp] * rinv, oT0[2 * rp + 1] * rinv);
            *reinterpret_cast<uint32_t*>(Y + yrow + 32 + d) =
                cvtpk(oT1[2 * rp] * rinv, oT1[2 * rp + 1] * rinv);
        }
    }
}

// ---------------- launch ----------------
extern "C" void kernel_launch(void* const* d_in, const int* in_sizes, int n_in,
                              void* d_out, int out_size, void* d_ws, size_t ws_size,
                              hipStream_t stream) {
    (void)in_sizes; (void)n_in; (void)out_size; (void)ws_size;
    const float* x     = (const float*)d_in[0];
    const float* wqkv  = (const float*)d_in[1];
    const float* wproj = (const float*)d_in[2];
    const float* fcos  = (const float*)d_in[3];
    const float* fsin  = (const float*)d_in[4];

    char* ws = (char*)d_ws;
    size_t off = 0;
    auto alloc = [&](size_t bytes) { void* p = ws + off; off += (bytes + 255) & ~(size_t)255; return p; };
    u16* Xbf  = (u16*)alloc((size_t)MM * CE * 2);
    u16* Wqb  = (u16*)alloc((size_t)QKVD * CE * 2);
    u16* Wpb  = (u16*)alloc((size_t)CE * CE * 2);
    u16* Qb   = (u16*)alloc((size_t)BB * NH * TT * HD * 2);
    u16* Kbuf = (u16*)alloc((size_t)BB * NKV * TT * HD * 2);
    u16* Vtb  = (u16*)alloc((size_t)BB * NKV * HD * TT * 2);
    u16* Yb   = (u16*)alloc((size_t)MM * CE * 2);

    k_f32_to_bf16<<<(MM * CE / 8 + 255) / 256, 256, 0, stream>>>(x, (uint32_t*)Xbf, MM * CE / 8);
    k_f32_to_bf16<<<(QKVD * CE / 8 + 255) / 256, 256, 0, stream>>>(wqkv, (uint32_t*)Wqb, QKVD * CE / 8);
    k_f32_to_bf16<<<(CE * CE / 8 + 255) / 256, 256, 0, stream>>>(wproj, (uint32_t*)Wpb, CE * CE / 8);

    dim3 g1(QKVD / 128, MM / 128);
    k_gemm_qkv<<<g1, 256, 0, stream>>>(Xbf, Wqb, Qb, Kbuf, Vtb, fcos, fsin);

    dim3 ga(8, NH, BB);
    k_attn<<<ga, 256, 0, stream>>>(Qb, Kbuf, Vtb, Yb);

    dim3 g2(CE / 128, MM / 128);
    k_gemm_bt<<<g2, 256, 0, stream>>>(Yb, Wpb, (float*)d_out, MM, CE, CE);
}